// Round 2
// baseline (1216.951 us; speedup 1.0000x reference)
//
#include <hip/hip_runtime.h>

typedef __bf16 bf16;
typedef __bf16 bf16x8 __attribute__((ext_vector_type(8)));
typedef float floatx4 __attribute__((ext_vector_type(4)));

#define N_NODES 50000
#define N_EDGES 800000
#define CAP 24  // max distinct dsts tracked per 128-edge block (overflow -> global atomics)

__device__ __forceinline__ float silu_f(float x) {
  float t = fminf(fmaxf(x, -40.f), 40.f);
  return x / (1.f + __expf(-t));
}
__device__ __forceinline__ float sigm_f(float x) {
  float t = fminf(fmaxf(x, -40.f), 40.f);
  return 1.f / (1.f + __expf(-t));
}

// LDS-only barrier: does NOT drain vmcnt, so global loads / atomics stay in flight.
__device__ __forceinline__ void bar_lds() {
  asm volatile("s_waitcnt lgkmcnt(0)" ::: "memory");
  __builtin_amdgcn_s_barrier();
  asm volatile("" ::: "memory");
}

// ---------------- prep: f32 -> bf16 ----------------
__global__ void prep_nf(const float* __restrict__ src, bf16* __restrict__ dst) {
  int i = (blockIdx.x * 256 + threadIdx.x) * 4;
  float4 v = *(const float4*)(src + i);
  bf16 o[4] = {(bf16)v.x, (bf16)v.y, (bf16)v.z, (bf16)v.w};
  *(float2*)(dst + i) = *(float2*)o;
}

// transpose+convert weights: Wt[n*Kp + k] = W[k*128 + n], zero-padded to Kp
struct TW { const float* s[5]; int K[5]; int Kp[5]; int off[5]; };
__global__ void prep_tw(TW j, bf16* __restrict__ out) {
  int g = blockIdx.x * 256 + threadIdx.x;
#pragma unroll
  for (int t = 0; t < 5; ++t) {
    int sz = 128 * j.Kp[t];
    if (g < sz) {
      int n = g / j.Kp[t], k = g - n * j.Kp[t];
      out[j.off[t] + g] = (k < j.K[t]) ? (bf16)j.s[t][(size_t)k * 128 + n] : (bf16)0.f;
      return;
    }
    g -= sz;
  }
}

// ---------------- counting sort of edges by dst ----------------
__global__ void hist_k(const int* __restrict__ dst, int* __restrict__ deg) {
  int e = blockIdx.x * 256 + threadIdx.x;
  if (e < N_EDGES) {
    int d = dst[e];
    if ((unsigned)d >= N_NODES) d = 0;
    atomicAdd(&deg[d], 1);
  }
}

__global__ void scan_k(const int* __restrict__ deg, int* __restrict__ start) {
  __shared__ int part[256];
  int t = threadIdx.x;
  int c0 = t * 196, c1 = min(N_NODES, c0 + 196);
  int s = 0;
  for (int i = c0; i < c1; ++i) s += deg[i];
  part[t] = s;
  __syncthreads();
  for (int off = 1; off < 256; off <<= 1) {
    int u = (t >= off) ? part[t - off] : 0;
    __syncthreads();
    part[t] += u;
    __syncthreads();
  }
  int run = part[t] - s;  // exclusive base
  for (int i = c0; i < c1; ++i) { start[i] = run; run += deg[i]; }
}

__global__ void scatter_k(const int* __restrict__ src, const int* __restrict__ dst,
                          int* __restrict__ start, int* __restrict__ eS,
                          int* __restrict__ srcS, int* __restrict__ dstS) {
  int e = blockIdx.x * 256 + threadIdx.x;
  if (e >= N_EDGES) return;
  int s = src[e], d = dst[e];
  if ((unsigned)s >= N_NODES) s = 0;
  if ((unsigned)d >= N_NODES) d = 0;
  int pos = atomicAdd(&start[d], 1);
  eS[pos] = e; srcS[pos] = s; dstS[pos] = d;
}

// W staging split into load-early / write-late: global->reg, then reg->LDS.
__device__ __forceinline__ void w_load(float4 wr[4], const bf16* __restrict__ Wt,
                                       int Kp, int kc, int tid) {
#pragma unroll
  for (int jj = 0; jj < 4; ++jj) {
    int g = tid + jj * 256;
    int n = g >> 3, c = g & 7;
    wr[jj] = *(const float4*)(Wt + (size_t)n * Kp + kc * 64 + c * 8);
  }
}
__device__ __forceinline__ void w_write(const float4 wr[4], bf16* __restrict__ Wl, int tid) {
#pragma unroll
  for (int jj = 0; jj < 4; ++jj) {
    int g = tid + jj * 256;
    int n = g >> 3, c = g & 7;
    *(float4*)(Wl + n * 64 + ((c ^ (n & 7)) << 3)) = wr[jj];
  }
}

// one 32-wide k-step: 8 col-tiles, B loaded once, 2 row-subtiles share it.
__device__ __forceinline__ void mfma_step(const bf16* __restrict__ Wl, int l15, int quad,
                                          bf16x8 a0, bf16x8 a1, int ks, floatx4 acc[2][8]) {
#pragma unroll
  for (int nt = 0; nt < 8; ++nt) {
    int n = nt * 16 + l15;
    bf16x8 b = *(const bf16x8*)(Wl + n * 64 + ((((ks >> 3) + quad) ^ (n & 7)) << 3));
    acc[0][nt] = __builtin_amdgcn_mfma_f32_16x16x32_bf16(a0, b, acc[0][nt], 0, 0, 0);
    acc[1][nt] = __builtin_amdgcn_mfma_f32_16x16x32_bf16(a1, b, acc[1][nt], 0, 0, 0);
  }
}

#define SX 136  // X stride (dword stride 68 === 4 mod 32 -> bank-group parallel floor)

// ---------------- pre kernel: P[n] = h[n] @ [W1a | W1b], bf16, BLOCKED layout ----
// P[node*256 + half*128 + l15*8 + nt] = (h @ W_e1[half-rows])[nt*16 + l15]
__global__ __launch_bounds__(256, 3) void pre_kernel(
    const bf16* __restrict__ nfb, const bf16* __restrict__ We1t,
    bf16* __restrict__ P) {
  __shared__ __align__(16) bf16 Wl[128 * 64];
  const int tid = threadIdx.x;
  const int lane = tid & 63;
  const int wv = tid >> 6;
  const int l15 = lane & 15;
  const int quad = lane >> 4;
  const int r0 = wv * 32;
  const int n0 = blockIdx.x * 128;

  bf16x8 A[2][2][2];  // [kc][t][s]
#pragma unroll
  for (int kc = 0; kc < 2; ++kc)
#pragma unroll
    for (int t = 0; t < 2; ++t) {
      int n = n0 + r0 + t * 16 + l15;
      bool ok = n < N_NODES;
#pragma unroll
      for (int s = 0; s < 2; ++s) {
        bf16x8 f = {};
        if (ok) f = *(const bf16x8*)(nfb + (size_t)n * 128 + kc * 64 + s * 32 + quad * 8);
        A[kc][t][s] = f;
      }
    }

  float4 wr[4];
  w_load(wr, We1t, 320, 0, tid);
  const floatx4 z4 = {0.f, 0.f, 0.f, 0.f};
#pragma unroll
  for (int h = 0; h < 2; ++h) {
    floatx4 acc[2][8];
#pragma unroll
    for (int t = 0; t < 2; ++t)
#pragma unroll
      for (int nt = 0; nt < 8; ++nt) acc[t][nt] = z4;
#pragma unroll
    for (int kc = 0; kc < 2; ++kc) {
      int c = h * 2 + kc;
      if (c > 0) bar_lds();
      w_write(wr, Wl, tid);
      if (c < 3) w_load(wr, We1t, 320, c + 1, tid);
      bar_lds();
      mfma_step(Wl, l15, quad, A[kc][0][0], A[kc][1][0], 0, acc);
      mfma_step(Wl, l15, quad, A[kc][0][1], A[kc][1][1], 32, acc);
    }
#pragma unroll
    for (int t = 0; t < 2; ++t)
#pragma unroll
      for (int i = 0; i < 4; ++i) {
        int node = n0 + r0 + t * 16 + quad * 4 + i;
        if (node < N_NODES) {
          bf16x8 v;
#pragma unroll
          for (int j = 0; j < 8; ++j) v[j] = (bf16)acc[t][j][i];
          *(bf16x8*)(P + (size_t)node * 256 + h * 128 + l15 * 8) = v;
        }
      }
  }
}

// ---------------- edge kernel: 128 dst-sorted edges/block ----------------
__global__ __launch_bounds__(256, 2) void edge_kernel(
    const bf16* __restrict__ P, const float* __restrict__ coords,
    const float* __restrict__ ef,
    const bf16* __restrict__ We1t, const float* __restrict__ be1,
    const bf16* __restrict__ We2t, const float* __restrict__ be2,
    const bf16* __restrict__ Wc1t, const float* __restrict__ bc1,
    const float* __restrict__ Wc, const float* __restrict__ Wa,
    const float* __restrict__ ba,
    const int* __restrict__ eS, const int* __restrict__ srcS,
    const int* __restrict__ dstS,
    float* __restrict__ m_agg, float* __restrict__ agg) {
  __shared__ __align__(16) bf16 X[128 * SX];   // h1, then gated m (rows wave-private)
  __shared__ __align__(16) bf16 Wl[128 * 64];  // swizzled W chunk
  __shared__ __align__(16) float Msum[CAP * 128];
  __shared__ float Asum[CAP * 3];
  __shared__ int sIdx[128], dIdx[128], eL[128];
  __shared__ float cdL[128][3];
  __shared__ float radL[128];
  __shared__ int sSlot[128];
  __shared__ int sDstOf[CAP];
  __shared__ int sND, sC0;

  const int tid = threadIdx.x;
  const int lane = tid & 63;
  const int wv = tid >> 6;
  const int l15 = lane & 15;
  const int quad = lane >> 4;
  const int r0 = wv * 32;
  const int e0 = blockIdx.x * 128;

  for (int i = tid; i < CAP * 128; i += 256) Msum[i] = 0.f;
  if (tid < CAP * 3) Asum[tid] = 0.f;

  if (tid < 128) {
    int row = e0 + tid;
    int s = srcS[row], d = dstS[row];
    sIdx[tid] = s; dIdx[tid] = d; eL[tid] = eS[row];
    float dx = coords[s * 3 + 0] - coords[d * 3 + 0];
    float dy = coords[s * 3 + 1] - coords[d * 3 + 1];
    float dz = coords[s * 3 + 2] - coords[d * 3 + 2];
    cdL[tid][0] = dx; cdL[tid][1] = dy; cdL[tid][2] = dz;
    radL[tid] = dx * dx + dy * dy + dz * dz;
  }
  bar_lds();

  // dst-segment slots via boundary-flag ballot prefix (rows are dst-sorted)
  bool flag = false; int incl = 0;
  if (tid < 128) {
    flag = (tid == 0) || (dIdx[tid] != dIdx[tid - 1]);
    unsigned long long m = __ballot(flag);
    incl = __popcll(m & (~0ull >> (63 - lane)));
    if (lane == 63 && tid < 64) sC0 = incl;
  }
  bar_lds();
  if (tid < 128) {
    int slot = ((tid >= 64) ? sC0 : 0) + incl - 1;
    sSlot[tid] = slot;
    if (flag && slot < CAP) sDstOf[slot] = dIdx[tid];
    if (tid == 127) sND = slot + 1;
  }

  // W chunk 0 (e1's radial/ef rows, k 256..319) issued before the P gather burst
  float4 wr[4];
  w_load(wr, We1t, 320, 4, tid);

  // ---- acc init: Pa[src] + Pb[dst] (bf16 P, f32 add) ----
  floatx4 acc[2][8];
#pragma unroll
  for (int t = 0; t < 2; ++t)
#pragma unroll
    for (int i = 0; i < 4; ++i) {
      int row = r0 + t * 16 + quad * 4 + i;
      bf16x8 pa = *(const bf16x8*)(P + (size_t)sIdx[row] * 256 + l15 * 8);
      bf16x8 pb = *(const bf16x8*)(P + (size_t)dIdx[row] * 256 + 128 + l15 * 8);
#pragma unroll
      for (int nt = 0; nt < 8; ++nt) acc[t][nt][i] = (float)pa[nt] + (float)pb[nt];
    }

  // ---- radial/ef A-frags (m_in cols 256..319) ----
  bf16x8 aef[2][2];
#pragma unroll
  for (int t = 0; t < 2; ++t) {
    int row = r0 + t * 16 + l15;
#pragma unroll
    for (int s = 0; s < 2; ++s)
#pragma unroll
      for (int jj = 0; jj < 8; ++jj) {
        int k = s * 32 + quad * 8 + jj;
        float v = 0.f;
        if (k == 0) v = radL[row];
        else if (k <= 32) v = ef[(size_t)eL[row] * 32 + (k - 1)];
        aef[t][s][jj] = (bf16)v;
      }
  }

  // ---- chunk 0: e1 radial/ef ----
  w_write(wr, Wl, tid);
  w_load(wr, We2t, 128, 0, tid);
  bar_lds();
  mfma_step(Wl, l15, quad, aef[0][0], aef[1][0], 0, acc);
  mfma_step(Wl, l15, quad, aef[0][1], aef[1][1], 32, acc);
#pragma unroll
  for (int t = 0; t < 2; ++t)
#pragma unroll
    for (int nt = 0; nt < 8; ++nt) {
      int col = nt * 16 + l15;
      float b = be1[col];
#pragma unroll
      for (int i = 0; i < 4; ++i) {
        X[(r0 + t * 16 + quad * 4 + i) * SX + col] = (bf16)silu_f(acc[t][nt][i] + b);
        acc[t][nt][i] = 0.f;
      }
    }
  bf16x8 aX[2][2][2];
#pragma unroll
  for (int kc = 0; kc < 2; ++kc)
#pragma unroll
    for (int t = 0; t < 2; ++t) {
      const bf16* p = X + (r0 + t * 16 + l15) * SX + kc * 64 + quad * 8;
      aX[kc][t][0] = *(const bf16x8*)(p);
      aX[kc][t][1] = *(const bf16x8*)(p + 32);
    }

  // ---- chunk 1: e2 kc0 ----
  bar_lds();
  w_write(wr, Wl, tid);
  w_load(wr, We2t, 128, 1, tid);
  bar_lds();
  mfma_step(Wl, l15, quad, aX[0][0][0], aX[0][1][0], 0, acc);
  mfma_step(Wl, l15, quad, aX[0][0][1], aX[0][1][1], 32, acc);
  // ---- chunk 2: e2 kc1 ----
  bar_lds();
  w_write(wr, Wl, tid);
  w_load(wr, Wc1t, 128, 0, tid);
  bar_lds();
  mfma_step(Wl, l15, quad, aX[1][0][0], aX[1][1][0], 0, acc);
  mfma_step(Wl, l15, quad, aX[1][0][1], aX[1][1][1], 32, acc);

  // epilogue e2: silu, attention gate, gated m -> X, segmented m-reduction to LDS
  float part[2][4] = {{0.f, 0.f, 0.f, 0.f}, {0.f, 0.f, 0.f, 0.f}};
#pragma unroll
  for (int t = 0; t < 2; ++t)
#pragma unroll
    for (int nt = 0; nt < 8; ++nt) {
      int col = nt * 16 + l15;
      float b = be2[col], wa = Wa[col];
#pragma unroll
      for (int i = 0; i < 4; ++i) {
        float v = silu_f(acc[t][nt][i] + b);
        acc[t][nt][i] = v;
        part[t][i] += v * wa;
      }
    }
#pragma unroll
  for (int off = 1; off < 16; off <<= 1)
#pragma unroll
    for (int t = 0; t < 2; ++t)
#pragma unroll
      for (int i = 0; i < 4; ++i) part[t][i] += __shfl_xor(part[t][i], off, 64);
  float ba_f = ba[0];
#pragma unroll
  for (int t = 0; t < 2; ++t)
#pragma unroll
    for (int i = 0; i < 4; ++i) {
      float g = sigm_f(part[t][i] + ba_f);
#pragma unroll
      for (int nt = 0; nt < 8; ++nt) acc[t][nt][i] *= g;
    }
#pragma unroll
  for (int t = 0; t < 2; ++t)
#pragma unroll
    for (int nt = 0; nt < 8; ++nt) {
      int col = nt * 16 + l15;
#pragma unroll
      for (int i = 0; i < 4; ++i)
        X[(r0 + t * 16 + quad * 4 + i) * SX + col] = (bf16)acc[t][nt][i];
    }
  // segmented reduction: rows sharing a dst sum in LDS; rare overflow -> global
#pragma unroll
  for (int t = 0; t < 2; ++t)
#pragma unroll
    for (int i = 0; i < 4; ++i) {
      int row = r0 + t * 16 + quad * 4 + i;
      int sl = sSlot[row];
      if (sl < CAP) {
#pragma unroll
        for (int nt = 0; nt < 8; ++nt)
          atomicAdd(&Msum[sl * 128 + nt * 16 + l15], acc[t][nt][i]);
      } else {
        size_t base = (size_t)dIdx[row] * 128;
#pragma unroll
        for (int nt = 0; nt < 8; ++nt)
          atomicAdd(&m_agg[base + nt * 16 + l15], acc[t][nt][i]);
      }
    }
#pragma unroll
  for (int t = 0; t < 2; ++t)
#pragma unroll
    for (int nt = 0; nt < 8; ++nt) acc[t][nt] = (floatx4){0.f, 0.f, 0.f, 0.f};

  bf16x8 aXc[2][2][2];
#pragma unroll
  for (int kc = 0; kc < 2; ++kc)
#pragma unroll
    for (int t = 0; t < 2; ++t) {
      const bf16* p = X + (r0 + t * 16 + l15) * SX + kc * 64 + quad * 8;
      aXc[kc][t][0] = *(const bf16x8*)(p);
      aXc[kc][t][1] = *(const bf16x8*)(p + 32);
    }

  // ---- chunk 3: coord kc0 (barrier here also fences all Msum ds_adds) ----
  bar_lds();
  w_write(wr, Wl, tid);
  w_load(wr, Wc1t, 128, 1, tid);
  {  // flush per-dst m sums: ~9 dsts x 128 cols per block
    int nD = min(sND, CAP);
    for (int idx = tid; idx < nD * 128; idx += 256) {
      int s = idx >> 7, c = idx & 127;
      atomicAdd(&m_agg[(size_t)sDstOf[s] * 128 + c], Msum[idx]);
    }
  }
  bar_lds();
  mfma_step(Wl, l15, quad, aXc[0][0][0], aXc[0][1][0], 0, acc);
  mfma_step(Wl, l15, quad, aXc[0][0][1], aXc[0][1][1], 32, acc);
  // ---- chunk 4: coord kc1 ----
  bar_lds();
  w_write(wr, Wl, tid);
  bar_lds();
  mfma_step(Wl, l15, quad, aXc[1][0][0], aXc[1][1][0], 0, acc);
  mfma_step(Wl, l15, quad, aXc[1][0][1], aXc[1][1][1], 32, acc);

  // coord epilogue: per-dst segmented sum of coord_diff * c
  float partc[2][4] = {{0.f, 0.f, 0.f, 0.f}, {0.f, 0.f, 0.f, 0.f}};
#pragma unroll
  for (int t = 0; t < 2; ++t)
#pragma unroll
    for (int nt = 0; nt < 8; ++nt) {
      int col = nt * 16 + l15;
      float b = bc1[col], wc = Wc[col];
#pragma unroll
      for (int i = 0; i < 4; ++i) partc[t][i] += silu_f(acc[t][nt][i] + b) * wc;
    }
#pragma unroll
  for (int off = 1; off < 16; off <<= 1)
#pragma unroll
    for (int t = 0; t < 2; ++t)
#pragma unroll
      for (int i = 0; i < 4; ++i) partc[t][i] += __shfl_xor(partc[t][i], off, 64);
  if (l15 == 0) {
#pragma unroll
    for (int t = 0; t < 2; ++t)
#pragma unroll
      for (int i = 0; i < 4; ++i) {
        int row = r0 + t * 16 + quad * 4 + i;
        int sl = sSlot[row];
        float c = partc[t][i];
        if (sl < CAP) {
          atomicAdd(&Asum[sl * 3 + 0], cdL[row][0] * c);
          atomicAdd(&Asum[sl * 3 + 1], cdL[row][1] * c);
          atomicAdd(&Asum[sl * 3 + 2], cdL[row][2] * c);
        } else {
          int d = dIdx[row];
          atomicAdd(&agg[d * 3 + 0], cdL[row][0] * c);
          atomicAdd(&agg[d * 3 + 1], cdL[row][1] * c);
          atomicAdd(&agg[d * 3 + 2], cdL[row][2] * c);
        }
      }
  }
  bar_lds();
  {
    int nD = min(sND, CAP);
    for (int idx = tid; idx < nD * 3; idx += 256)
      atomicAdd(&agg[sDstOf[idx / 3] * 3 + idx % 3], Asum[idx]);
  }
}

// ---------------- node kernel: 128 nodes/block ----------------
__device__ __forceinline__ void load_a_node(int kc, int n0, int r0, int l15, int quad,
                                            const bf16* __restrict__ nfb,
                                            const float* __restrict__ m_agg,
                                            bf16x8 a[2][2]) {
#pragma unroll
  for (int t = 0; t < 2; ++t) {
    int n = n0 + r0 + t * 16 + l15;
    bool ok = n < N_NODES;
#pragma unroll
    for (int s = 0; s < 2; ++s) {
      bf16x8 f = {};
      if (kc < 2) {
        if (ok) f = *(const bf16x8*)(nfb + (size_t)n * 128 + kc * 64 + s * 32 + quad * 8);
      } else if (ok) {
        const float* p = m_agg + (size_t)n * 128 + (kc - 2) * 64 + s * 32 + quad * 8;
        float4 u0 = *(const float4*)(p);
        float4 u1 = *(const float4*)(p + 4);
        f[0] = (bf16)u0.x; f[1] = (bf16)u0.y; f[2] = (bf16)u0.z; f[3] = (bf16)u0.w;
        f[4] = (bf16)u1.x; f[5] = (bf16)u1.y; f[6] = (bf16)u1.z; f[7] = (bf16)u1.w;
      }
      a[t][s] = f;
    }
  }
}

__global__ __launch_bounds__(256, 3) void node_kernel(
    const bf16* __restrict__ nfb, const float* __restrict__ nf,
    const float* __restrict__ coords,
    const bf16* __restrict__ Wn1t, const float* __restrict__ bn1,
    const bf16* __restrict__ Wn2t, const float* __restrict__ bn2,
    const float* __restrict__ m_agg, const float* __restrict__ agg,
    const int* __restrict__ deg,
    float* __restrict__ h_out, float* __restrict__ c_out) {
  __shared__ __align__(16) bf16 X[128 * SX];
  __shared__ __align__(16) bf16 Wl[128 * 64];

  const int tid = threadIdx.x;
  const int lane = tid & 63;
  const int wv = tid >> 6;
  const int l15 = lane & 15;
  const int quad = lane >> 4;
  const int r0 = wv * 32;
  const int n0 = blockIdx.x * 128;

  if (tid < 128) {
    int n = n0 + tid;
    if (n < N_NODES) {
      float inv = 1.f / fmaxf((float)deg[n], 1.f);
#pragma unroll
      for (int j = 0; j < 3; ++j)
        c_out[n * 3 + j] = coords[n * 3 + j] + agg[n * 3 + j] * inv;
    }
  }

  const floatx4 z4 = {0.f, 0.f, 0.f, 0.f};
  floatx4 acc[2][8];
#pragma unroll
  for (int t = 0; t < 2; ++t)
#pragma unroll
    for (int nt = 0; nt < 8; ++nt) acc[t][nt] = z4;

  float4 wr[4];
  w_load(wr, Wn1t, 256, 0, tid);
  bf16x8 a_cur[2][2], a_nxt[2][2];
  load_a_node(0, n0, r0, l15, quad, nfb, m_agg, a_cur);

#pragma unroll
  for (int c = 0; c < 4; ++c) {
    if (c > 0) bar_lds();
    w_write(wr, Wl, tid);
    if (c < 3) {
      w_load(wr, Wn1t, 256, c + 1, tid);
      load_a_node(c + 1, n0, r0, l15, quad, nfb, m_agg, a_nxt);
    } else {
      w_load(wr, Wn2t, 128, 0, tid);
    }
    bar_lds();
    mfma_step(Wl, l15, quad, a_cur[0][0], a_cur[1][0], 0, acc);
    mfma_step(Wl, l15, quad, a_cur[0][1], a_cur[1][1], 32, acc);
    if (c < 3) {
#pragma unroll
      for (int t = 0; t < 2; ++t)
#pragma unroll
        for (int s = 0; s < 2; ++s) a_cur[t][s] = a_nxt[t][s];
    }
  }
#pragma unroll
  for (int t = 0; t < 2; ++t)
#pragma unroll
    for (int nt = 0; nt < 8; ++nt) {
      int col = nt * 16 + l15;
      float b = bn1[col];
#pragma unroll
      for (int i = 0; i < 4; ++i) {
        X[(r0 + t * 16 + quad * 4 + i) * SX + col] = (bf16)silu_f(acc[t][nt][i] + b);
        acc[t][nt][i] = 0.f;
      }
    }
  bf16x8 aX[2][2][2];
#pragma unroll
  for (int kc = 0; kc < 2; ++kc)
#pragma unroll
    for (int t = 0; t < 2; ++t) {
      const bf16* p = X + (r0 + t * 16 + l15) * SX + kc * 64 + quad * 8;
      aX[kc][t][0] = *(const bf16x8*)(p);
      aX[kc][t][1] = *(const bf16x8*)(p + 32);
    }

  bar_lds();
  w_write(wr, Wl, tid);
  w_load(wr, Wn2t, 128, 1, tid);
  bar_lds();
  mfma_step(Wl, l15, quad, aX[0][0][0], aX[0][1][0], 0, acc);
  mfma_step(Wl, l15, quad, aX[0][0][1], aX[0][1][1], 32, acc);
  bar_lds();
  w_write(wr, Wl, tid);
  bar_lds();
  mfma_step(Wl, l15, quad, aX[1][0][0], aX[1][1][0], 0, acc);
  mfma_step(Wl, l15, quad, aX[1][0][1], aX[1][1][1], 32, acc);

#pragma unroll
  for (int t = 0; t < 2; ++t)
#pragma unroll
    for (int nt = 0; nt < 8; ++nt) {
      int col = nt * 16 + l15;
      float b = bn2[col];
#pragma unroll
      for (int i = 0; i < 4; ++i) {
        int n = n0 + r0 + t * 16 + quad * 4 + i;
        if (n < N_NODES)
          h_out[(size_t)n * 128 + col] = nf[(size_t)n * 128 + col] + acc[t][nt][i] + b;
      }
    }
}

extern "C" void kernel_launch(void* const* d_in, const int* in_sizes, int n_in,
                              void* d_out, int out_size, void* d_ws, size_t ws_size,
                              hipStream_t stream) {
  const float* nf     = (const float*)d_in[0];
  const float* coords = (const float*)d_in[1];
  const float* ef     = (const float*)d_in[2];
  const float* We1    = (const float*)d_in[3];
  const float* be1    = (const float*)d_in[4];
  const float* We2    = (const float*)d_in[5];
  const float* be2    = (const float*)d_in[6];
  const float* Wn1    = (const float*)d_in[7];
  const float* bn1    = (const float*)d_in[8];
  const float* Wn2    = (const float*)d_in[9];
  const float* bn2    = (const float*)d_in[10];
  const float* Wc1    = (const float*)d_in[11];
  const float* bc1    = (const float*)d_in[12];
  const float* Wc     = (const float*)d_in[13];
  const float* Wa     = (const float*)d_in[14];
  const float* ba     = (const float*)d_in[15];
  const int*   src    = (const int*)d_in[16];
  const int*   dst    = (const int*)d_in[17];

  // workspace layout (zeroed region first)
  int*   deg   = (int*)d_ws;                          // N   (zeroed)
  float* agg   = (float*)(deg + N_NODES);             // 3N  (zeroed)
  float* m_agg = agg + (size_t)3 * N_NODES;           // 128N (zeroed)
  int*   start = (int*)(m_agg + (size_t)N_NODES * 128);  // N
  int*   eS    = start + N_NODES;                     // E
  int*   srcS  = eS + N_EDGES;                        // E
  int*   dstS  = srcS + N_EDGES;                      // E
  bf16*  nfb   = (bf16*)(dstS + N_EDGES);             // 128N
  bf16*  Wt    = nfb + (size_t)N_NODES * 128;         // 122880
  bf16*  P     = Wt + 122880;                         // 256N (blocked)

  const int offE1 = 0;
  const int offE2 = 128 * 320;
  const int offC1 = offE2 + 128 * 128;
  const int offN1 = offC1 + 128 * 128;
  const int offN2 = offN1 + 128 * 256;

  size_t zb = ((size_t)N_NODES * (1 + 3 + 128)) * 4;
  hipMemsetAsync(d_ws, 0, zb, stream);

  prep_nf<<<(N_NODES * 128) / (256 * 4), 256, 0, stream>>>(nf, nfb);
  TW tw;
  tw.s[0] = We1; tw.K[0] = 289; tw.Kp[0] = 320; tw.off[0] = offE1;
  tw.s[1] = We2; tw.K[1] = 128; tw.Kp[1] = 128; tw.off[1] = offE2;
  tw.s[2] = Wc1; tw.K[2] = 128; tw.Kp[2] = 128; tw.off[2] = offC1;
  tw.s[3] = Wn1; tw.K[3] = 256; tw.Kp[3] = 256; tw.off[3] = offN1;
  tw.s[4] = Wn2; tw.K[4] = 128; tw.Kp[4] = 128; tw.off[4] = offN2;
  prep_tw<<<480, 256, 0, stream>>>(tw, Wt);

  hist_k<<<(N_EDGES + 255) / 256, 256, 0, stream>>>(dst, deg);
  scan_k<<<1, 256, 0, stream>>>(deg, start);
  scatter_k<<<(N_EDGES + 255) / 256, 256, 0, stream>>>(src, dst, start, eS, srcS, dstS);

  pre_kernel<<<(N_NODES + 127) / 128, 256, 0, stream>>>(nfb, Wt + offE1, P);

  float* h_out = (float*)d_out;
  float* c_out = h_out + (size_t)N_NODES * 128;

  edge_kernel<<<N_EDGES / 128, 256, 0, stream>>>(
      P, coords, ef, Wt + offE1, be1, Wt + offE2, be2, Wt + offC1, bc1,
      Wc, Wa, ba, eS, srcS, dstS, m_agg, agg);
  node_kernel<<<(N_NODES + 127) / 128, 256, 0, stream>>>(
      nfb, nf, coords, Wt + offN1, bn1, Wt + offN2, bn2,
      m_agg, agg, deg, h_out, c_out);
}

// Round 4
// 737.429 us; speedup vs baseline: 1.6503x; 1.6503x over previous
//
#include <hip/hip_runtime.h>

typedef __bf16 bf16;
typedef __bf16 bf16x8 __attribute__((ext_vector_type(8)));
typedef float floatx4 __attribute__((ext_vector_type(4)));

#define N_NODES 50000
#define N_EDGES 800000

__device__ __forceinline__ float silu_f(float x) {
  float t = fminf(fmaxf(x, -40.f), 40.f);
  return x / (1.f + __expf(-t));
}
__device__ __forceinline__ float sigm_f(float x) {
  float t = fminf(fmaxf(x, -40.f), 40.f);
  return 1.f / (1.f + __expf(-t));
}

// ---------------- prep: f32 -> bf16 ----------------
__global__ void prep_nf(const float* __restrict__ src, bf16* __restrict__ dst) {
  int i = (blockIdx.x * 256 + threadIdx.x) * 4;
  float4 v = *(const float4*)(src + i);
  bf16 o[4] = {(bf16)v.x, (bf16)v.y, (bf16)v.z, (bf16)v.w};
  *(float2*)(dst + i) = *(float2*)o;
}

// transpose+convert weights: Wt[n*Kp + k] = W[k*128 + n], zero-padded to Kp
struct TW { const float* s[5]; int K[5]; int Kp[5]; int off[5]; };
__global__ void prep_tw(TW j, bf16* __restrict__ out) {
  int g = blockIdx.x * 256 + threadIdx.x;
#pragma unroll
  for (int t = 0; t < 5; ++t) {
    int sz = 128 * j.Kp[t];
    if (g < sz) {
      int n = g / j.Kp[t], k = g - n * j.Kp[t];
      out[j.off[t] + g] = (k < j.K[t]) ? (bf16)j.s[t][(size_t)k * 128 + n] : (bf16)0.f;
      return;
    }
    g -= sz;
  }
}

// stage one 64-wide K-chunk of Wt into LDS [128][64] with XOR chunk swizzle.
__device__ __forceinline__ void stage_w(bf16* __restrict__ Wl, const bf16* __restrict__ Wt,
                                        int Kp, int kc, int tid) {
#pragma unroll
  for (int jj = 0; jj < 4; ++jj) {
    int g = tid + jj * 256;
    int n = g >> 3, c = g & 7;
    *(float4*)(Wl + n * 64 + ((c ^ (n & 7)) << 3)) =
        *(const float4*)(Wt + (size_t)n * Kp + kc * 64 + c * 8);
  }
}

// one 32-wide k-step: 8 col-tiles, B loaded once, 2 row-subtiles share it.
__device__ __forceinline__ void mfma_step(const bf16* __restrict__ Wl, int l15, int quad,
                                          bf16x8 a0, bf16x8 a1, int ks, floatx4 acc[2][8]) {
#pragma unroll
  for (int nt = 0; nt < 8; ++nt) {
    int n = nt * 16 + l15;
    bf16x8 b = *(const bf16x8*)(Wl + n * 64 + ((((ks >> 3) + quad) ^ (n & 7)) << 3));
    acc[0][nt] = __builtin_amdgcn_mfma_f32_16x16x32_bf16(a0, b, acc[0][nt], 0, 0, 0);
    acc[1][nt] = __builtin_amdgcn_mfma_f32_16x16x32_bf16(a1, b, acc[1][nt], 0, 0, 0);
  }
}

// X tile: [128][128] bf16, 16B-chunk XOR swizzle.
// chunk' = (col>>3) ^ (row&7): XOR with a 3-bit value flips only bits 0..2,
// preserving bit 3 of the 4-bit chunk index -> bijective per row.
__device__ __forceinline__ int xidx(int row, int col) {
  return row * 128 + ((((col >> 3) ^ (row & 7))) << 3) + (col & 7);
}

// ---------------- edge kernel: 128 edges/block, 4 waves x 32 rows ----------------
__global__ __launch_bounds__(256, 3) void edge_kernel(
    const bf16* __restrict__ nfb, const float* __restrict__ coords,
    const float* __restrict__ ef,
    const bf16* __restrict__ We1t, const float* __restrict__ be1,
    const bf16* __restrict__ We2t, const float* __restrict__ be2,
    const bf16* __restrict__ Wc1t, const float* __restrict__ bc1,
    const float* __restrict__ Wc, const float* __restrict__ Wa,
    const float* __restrict__ ba,
    const int* __restrict__ src, const int* __restrict__ dst,
    float* __restrict__ m_agg, float* __restrict__ agg, float* __restrict__ cnt) {
  __shared__ __align__(16) bf16 X[128 * 128];  // h1, then gated m (rows wave-private)
  __shared__ __align__(16) bf16 Wl[128 * 64];  // swizzled W chunk
  __shared__ int sIdx[128], dIdx[128];
  __shared__ float cdL[128][3];
  __shared__ float radL[128];

  const int tid = threadIdx.x;
  const int lane = tid & 63;
  const int wv = tid >> 6;
  const int l15 = lane & 15;
  const int quad = lane >> 4;
  const int r0 = wv * 32;
  const int e0 = blockIdx.x * 128;

  if (tid < 128) {
    int e = e0 + tid;
    int s = src[e], d = dst[e];
    if ((unsigned)s >= N_NODES) s = 0;
    if ((unsigned)d >= N_NODES) d = 0;
    sIdx[tid] = s; dIdx[tid] = d;
    float dx = coords[s * 3 + 0] - coords[d * 3 + 0];
    float dy = coords[s * 3 + 1] - coords[d * 3 + 1];
    float dz = coords[s * 3 + 2] - coords[d * 3 + 2];
    cdL[tid][0] = dx; cdL[tid][1] = dy; cdL[tid][2] = dz;
    radL[tid] = dx * dx + dy * dy + dz * dz;
  }
  __syncthreads();

  const floatx4 z4 = {0.f, 0.f, 0.f, 0.f};
  floatx4 acc[2][8];
#pragma unroll
  for (int t = 0; t < 2; ++t)
#pragma unroll
    for (int nt = 0; nt < 8; ++nt) acc[t][nt] = z4;

  // ---- layer e1: K=320 (289 real), kc 0..4; A-frags gathered from global ----
  for (int kc = 0; kc < 5; ++kc) {
    __syncthreads();
    bf16x8 a[2][2];
#pragma unroll
    for (int t = 0; t < 2; ++t) {
      int row = r0 + t * 16 + l15;
      if (kc < 4) {
        int node = (kc < 2) ? sIdx[row] : dIdx[row];
        const bf16* p = nfb + (size_t)node * 128 + (kc & 1) * 64 + quad * 8;
        a[t][0] = *(const bf16x8*)(p);
        a[t][1] = *(const bf16x8*)(p + 32);
      } else {
#pragma unroll
        for (int s = 0; s < 2; ++s)
#pragma unroll
          for (int jj = 0; jj < 8; ++jj) {
            int k = s * 32 + quad * 8 + jj;   // m_in col 256+k
            float v = 0.f;
            if (k == 0) v = radL[row];
            else if (k <= 32) v = ef[(size_t)(e0 + row) * 32 + (k - 1)];
            a[t][s][jj] = (bf16)v;
          }
      }
    }
    stage_w(Wl, We1t, 320, kc, tid);
    __syncthreads();
    mfma_step(Wl, l15, quad, a[0][0], a[1][0], 0, acc);
    mfma_step(Wl, l15, quad, a[0][1], a[1][1], 32, acc);
  }
  // epilogue e1: h1 = silu(acc+b) -> X
#pragma unroll
  for (int t = 0; t < 2; ++t)
#pragma unroll
    for (int nt = 0; nt < 8; ++nt) {
      int col = nt * 16 + l15;
      float b = be1[col];
#pragma unroll
      for (int i = 0; i < 4; ++i) {
        X[xidx(r0 + t * 16 + quad * 4 + i, col)] = (bf16)silu_f(acc[t][nt][i] + b);
        acc[t][nt][i] = 0.f;
      }
    }

  // ---- layer e2: K=128, A from X ----
  for (int kc = 0; kc < 2; ++kc) {
    __syncthreads();
    bf16x8 a[2][2];
#pragma unroll
    for (int t = 0; t < 2; ++t) {
      int row = r0 + t * 16 + l15;
      a[t][0] = *(const bf16x8*)(X + xidx(row, kc * 64 + quad * 8));
      a[t][1] = *(const bf16x8*)(X + xidx(row, kc * 64 + quad * 8 + 32));
    }
    stage_w(Wl, We2t, 128, kc, tid);
    __syncthreads();
    mfma_step(Wl, l15, quad, a[0][0], a[1][0], 0, acc);
    mfma_step(Wl, l15, quad, a[0][1], a[1][1], 32, acc);
  }
  // epilogue e2: silu, attention gate, write gated m to X, scatter m_agg
  float part[2][4] = {{0.f, 0.f, 0.f, 0.f}, {0.f, 0.f, 0.f, 0.f}};
#pragma unroll
  for (int t = 0; t < 2; ++t)
#pragma unroll
    for (int nt = 0; nt < 8; ++nt) {
      int col = nt * 16 + l15;
      float b = be2[col], wa = Wa[col];
#pragma unroll
      for (int i = 0; i < 4; ++i) {
        float v = silu_f(acc[t][nt][i] + b);
        acc[t][nt][i] = v;
        part[t][i] += v * wa;
      }
    }
#pragma unroll
  for (int off = 1; off < 16; off <<= 1)
#pragma unroll
    for (int t = 0; t < 2; ++t)
#pragma unroll
      for (int i = 0; i < 4; ++i) part[t][i] += __shfl_xor(part[t][i], off, 64);
  float ba_f = ba[0];
#pragma unroll
  for (int t = 0; t < 2; ++t)
#pragma unroll
    for (int i = 0; i < 4; ++i) {
      float g = sigm_f(part[t][i] + ba_f);
#pragma unroll
      for (int nt = 0; nt < 8; ++nt) acc[t][nt][i] *= g;
    }
#pragma unroll
  for (int t = 0; t < 2; ++t)
#pragma unroll
    for (int nt = 0; nt < 8; ++nt) {
      int col = nt * 16 + l15;
#pragma unroll
      for (int i = 0; i < 4; ++i)
        X[xidx(r0 + t * 16 + quad * 4 + i, col)] = (bf16)acc[t][nt][i];
    }
  // scatter gated m (f32 atomics) — issued early so they overlap layer 3
#pragma unroll
  for (int t = 0; t < 2; ++t)
#pragma unroll
    for (int i = 0; i < 4; ++i) {
      int row = r0 + t * 16 + quad * 4 + i;
      size_t base = (size_t)dIdx[row] * 128;
#pragma unroll
      for (int nt = 0; nt < 8; ++nt)
        atomicAdd(&m_agg[base + nt * 16 + l15], acc[t][nt][i]);
    }
#pragma unroll
  for (int t = 0; t < 2; ++t)
#pragma unroll
    for (int nt = 0; nt < 8; ++nt) acc[t][nt] = z4;

  // ---- coord layer: K=128, A = gated m from X ----
  for (int kc = 0; kc < 2; ++kc) {
    __syncthreads();
    bf16x8 a[2][2];
#pragma unroll
    for (int t = 0; t < 2; ++t) {
      int row = r0 + t * 16 + l15;
      a[t][0] = *(const bf16x8*)(X + xidx(row, kc * 64 + quad * 8));
      a[t][1] = *(const bf16x8*)(X + xidx(row, kc * 64 + quad * 8 + 32));
    }
    stage_w(Wl, Wc1t, 128, kc, tid);
    __syncthreads();
    mfma_step(Wl, l15, quad, a[0][0], a[1][0], 0, acc);
    mfma_step(Wl, l15, quad, a[0][1], a[1][1], 32, acc);
  }
  float partc[2][4] = {{0.f, 0.f, 0.f, 0.f}, {0.f, 0.f, 0.f, 0.f}};
#pragma unroll
  for (int t = 0; t < 2; ++t)
#pragma unroll
    for (int nt = 0; nt < 8; ++nt) {
      int col = nt * 16 + l15;
      float b = bc1[col], wc = Wc[col];
#pragma unroll
      for (int i = 0; i < 4; ++i) partc[t][i] += silu_f(acc[t][nt][i] + b) * wc;
    }
#pragma unroll
  for (int off = 1; off < 16; off <<= 1)
#pragma unroll
    for (int t = 0; t < 2; ++t)
#pragma unroll
      for (int i = 0; i < 4; ++i) partc[t][i] += __shfl_xor(partc[t][i], off, 64);
  if (l15 == 0) {
#pragma unroll
    for (int t = 0; t < 2; ++t)
#pragma unroll
      for (int i = 0; i < 4; ++i) {
        int row = r0 + t * 16 + quad * 4 + i;
        int d = dIdx[row];
        float c = partc[t][i];
        atomicAdd(&agg[d * 3 + 0], cdL[row][0] * c);
        atomicAdd(&agg[d * 3 + 1], cdL[row][1] * c);
        atomicAdd(&agg[d * 3 + 2], cdL[row][2] * c);
        atomicAdd(&cnt[d], 1.0f);
      }
  }
}

// ---------------- node kernel: 128 nodes/block ----------------
__global__ __launch_bounds__(256, 3) void node_kernel(
    const bf16* __restrict__ nfb, const float* __restrict__ nf,
    const float* __restrict__ coords,
    const bf16* __restrict__ Wn1t, const float* __restrict__ bn1,
    const bf16* __restrict__ Wn2t, const float* __restrict__ bn2,
    const float* __restrict__ m_agg, const float* __restrict__ agg,
    const float* __restrict__ cnt,
    float* __restrict__ h_out, float* __restrict__ c_out) {
  __shared__ __align__(16) bf16 X[128 * 128];
  __shared__ __align__(16) bf16 Wl[128 * 64];

  const int tid = threadIdx.x;
  const int lane = tid & 63;
  const int wv = tid >> 6;
  const int l15 = lane & 15;
  const int quad = lane >> 4;
  const int r0 = wv * 32;
  const int n0 = blockIdx.x * 128;

  if (tid < 128) {
    int n = n0 + tid;
    if (n < N_NODES) {
      float inv = 1.f / fmaxf(cnt[n], 1.f);
#pragma unroll
      for (int j = 0; j < 3; ++j)
        c_out[n * 3 + j] = coords[n * 3 + j] + agg[n * 3 + j] * inv;
    }
  }

  const floatx4 z4 = {0.f, 0.f, 0.f, 0.f};
  floatx4 acc[2][8];
#pragma unroll
  for (int t = 0; t < 2; ++t)
#pragma unroll
    for (int nt = 0; nt < 8; ++nt) acc[t][nt] = z4;

  // ---- n1: K=256 (cols 0-127 h from nfb, 128-255 m_agg f32->bf16) ----
  for (int kc = 0; kc < 4; ++kc) {
    __syncthreads();
    bf16x8 a[2][2];
#pragma unroll
    for (int t = 0; t < 2; ++t) {
      int n = n0 + r0 + t * 16 + l15;
      bool ok = n < N_NODES;
#pragma unroll
      for (int s = 0; s < 2; ++s) {
        if (kc < 2) {
          bf16x8 f = {};
          if (ok) f = *(const bf16x8*)(nfb + (size_t)n * 128 + kc * 64 + s * 32 + quad * 8);
          a[t][s] = f;
        } else {
          bf16x8 f;
          if (ok) {
            const float* p = m_agg + (size_t)n * 128 + (kc - 2) * 64 + s * 32 + quad * 8;
            float4 u0 = *(const float4*)(p);
            float4 u1 = *(const float4*)(p + 4);
            f[0] = (bf16)u0.x; f[1] = (bf16)u0.y; f[2] = (bf16)u0.z; f[3] = (bf16)u0.w;
            f[4] = (bf16)u1.x; f[5] = (bf16)u1.y; f[6] = (bf16)u1.z; f[7] = (bf16)u1.w;
          } else {
            bf16x8 zz = {};
            f = zz;
          }
          a[t][s] = f;
        }
      }
    }
    stage_w(Wl, Wn1t, 256, kc, tid);
    __syncthreads();
    mfma_step(Wl, l15, quad, a[0][0], a[1][0], 0, acc);
    mfma_step(Wl, l15, quad, a[0][1], a[1][1], 32, acc);
  }
#pragma unroll
  for (int t = 0; t < 2; ++t)
#pragma unroll
    for (int nt = 0; nt < 8; ++nt) {
      int col = nt * 16 + l15;
      float b = bn1[col];
#pragma unroll
      for (int i = 0; i < 4; ++i) {
        X[xidx(r0 + t * 16 + quad * 4 + i, col)] = (bf16)silu_f(acc[t][nt][i] + b);
        acc[t][nt][i] = 0.f;
      }
    }

  // ---- n2: K=128, A = h1 from X; residual from f32 nf ----
  for (int kc = 0; kc < 2; ++kc) {
    __syncthreads();
    bf16x8 a[2][2];
#pragma unroll
    for (int t = 0; t < 2; ++t) {
      int row = r0 + t * 16 + l15;
      a[t][0] = *(const bf16x8*)(X + xidx(row, kc * 64 + quad * 8));
      a[t][1] = *(const bf16x8*)(X + xidx(row, kc * 64 + quad * 8 + 32));
    }
    stage_w(Wl, Wn2t, 128, kc, tid);
    __syncthreads();
    mfma_step(Wl, l15, quad, a[0][0], a[1][0], 0, acc);
    mfma_step(Wl, l15, quad, a[0][1], a[1][1], 32, acc);
  }
#pragma unroll
  for (int t = 0; t < 2; ++t)
#pragma unroll
    for (int nt = 0; nt < 8; ++nt) {
      int col = nt * 16 + l15;
      float b = bn2[col];
#pragma unroll
      for (int i = 0; i < 4; ++i) {
        int n = n0 + r0 + t * 16 + quad * 4 + i;
        if (n < N_NODES)
          h_out[(size_t)n * 128 + col] = nf[(size_t)n * 128 + col] + acc[t][nt][i] + b;
      }
    }
}

extern "C" void kernel_launch(void* const* d_in, const int* in_sizes, int n_in,
                              void* d_out, int out_size, void* d_ws, size_t ws_size,
                              hipStream_t stream) {
  const float* nf     = (const float*)d_in[0];
  const float* coords = (const float*)d_in[1];
  const float* ef     = (const float*)d_in[2];
  const float* We1    = (const float*)d_in[3];
  const float* be1    = (const float*)d_in[4];
  const float* We2    = (const float*)d_in[5];
  const float* be2    = (const float*)d_in[6];
  const float* Wn1    = (const float*)d_in[7];
  const float* bn1    = (const float*)d_in[8];
  const float* Wn2    = (const float*)d_in[9];
  const float* bn2    = (const float*)d_in[10];
  const float* Wc1    = (const float*)d_in[11];
  const float* bc1    = (const float*)d_in[12];
  const float* Wc     = (const float*)d_in[13];
  const float* Wa     = (const float*)d_in[14];
  const float* ba     = (const float*)d_in[15];
  const int*   src    = (const int*)d_in[16];
  const int*   dst    = (const int*)d_in[17];

  float* agg   = (float*)d_ws;                      // 3N
  float* cnt   = agg + (size_t)3 * N_NODES;         // N
  float* m_agg = cnt + N_NODES;                     // N*128
  bf16* nfb    = (bf16*)(m_agg + (size_t)N_NODES * 128);
  bf16* Wt     = nfb + (size_t)N_NODES * 128;       // 122880 bf16
  const int offE1 = 0;
  const int offE2 = 128 * 320;
  const int offC1 = offE2 + 128 * 128;
  const int offN1 = offC1 + 128 * 128;
  const int offN2 = offN1 + 128 * 256;

  size_t zb = ((size_t)3 * N_NODES + N_NODES + (size_t)N_NODES * 128) * sizeof(float);
  hipMemsetAsync(d_ws, 0, zb, stream);

  prep_nf<<<(N_NODES * 128) / (256 * 4), 256, 0, stream>>>(nf, nfb);
  TW tw;
  tw.s[0] = We1; tw.K[0] = 289; tw.Kp[0] = 320; tw.off[0] = offE1;
  tw.s[1] = We2; tw.K[1] = 128; tw.Kp[1] = 128; tw.off[1] = offE2;
  tw.s[2] = Wc1; tw.K[2] = 128; tw.Kp[2] = 128; tw.off[2] = offC1;
  tw.s[3] = Wn1; tw.K[3] = 256; tw.Kp[3] = 256; tw.off[3] = offN1;
  tw.s[4] = Wn2; tw.K[4] = 128; tw.Kp[4] = 128; tw.off[4] = offN2;
  prep_tw<<<480, 256, 0, stream>>>(tw, Wt);

  float* h_out = (float*)d_out;
  float* c_out = h_out + (size_t)N_NODES * 128;

  edge_kernel<<<N_EDGES / 128, 256, 0, stream>>>(
      nfb, coords, ef, Wt + offE1, be1, Wt + offE2, be2, Wt + offC1, bc1,
      Wc, Wa, ba, src, dst, m_agg, agg, cnt);
  node_kernel<<<(N_NODES + 127) / 128, 256, 0, stream>>>(
      nfb, nf, coords, Wt + offN1, bn1, Wt + offN2, bn2,
      m_agg, agg, cnt, h_out, c_out);
}

// Round 5
// 731.039 us; speedup vs baseline: 1.6647x; 1.0087x over previous
//
#include <hip/hip_runtime.h>

typedef __bf16 bf16;
typedef __bf16 bf16x8 __attribute__((ext_vector_type(8)));
typedef float floatx4 __attribute__((ext_vector_type(4)));

#define N_NODES 50000
#define N_EDGES 800000

__device__ __forceinline__ float silu_f(float x) {
  float t = fminf(fmaxf(x, -40.f), 40.f);
  return x / (1.f + __expf(-t));
}
__device__ __forceinline__ float sigm_f(float x) {
  float t = fminf(fmaxf(x, -40.f), 40.f);
  return 1.f / (1.f + __expf(-t));
}

// ---------------- prep: f32 -> bf16 ----------------
__global__ void prep_nf(const float* __restrict__ src, bf16* __restrict__ dst) {
  int i = (blockIdx.x * 256 + threadIdx.x) * 4;
  float4 v = *(const float4*)(src + i);
  bf16 o[4] = {(bf16)v.x, (bf16)v.y, (bf16)v.z, (bf16)v.w};
  *(float2*)(dst + i) = *(float2*)o;
}

// transpose+convert weights: Wt[n*Kp + k] = W[k*128 + n], zero-padded to Kp
struct TW { const float* s[5]; int K[5]; int Kp[5]; int off[5]; };
__global__ void prep_tw(TW j, bf16* __restrict__ out) {
  int g = blockIdx.x * 256 + threadIdx.x;
#pragma unroll
  for (int t = 0; t < 5; ++t) {
    int sz = 128 * j.Kp[t];
    if (g < sz) {
      int n = g / j.Kp[t], k = g - n * j.Kp[t];
      out[j.off[t] + g] = (k < j.K[t]) ? (bf16)j.s[t][(size_t)k * 128 + n] : (bf16)0.f;
      return;
    }
    g -= sz;
  }
}

// stage one 64-wide K-chunk of Wt into LDS [128][64] with XOR chunk swizzle.
__device__ __forceinline__ void stage_w(bf16* __restrict__ Wl, const bf16* __restrict__ Wt,
                                        int Kp, int kc, int tid) {
#pragma unroll
  for (int jj = 0; jj < 4; ++jj) {
    int g = tid + jj * 256;
    int n = g >> 3, c = g & 7;
    *(float4*)(Wl + n * 64 + ((c ^ (n & 7)) << 3)) =
        *(const float4*)(Wt + (size_t)n * Kp + kc * 64 + c * 8);
  }
}

// one 32-wide k-step: 8 col-tiles, B loaded once, 2 row-subtiles share it.
__device__ __forceinline__ void mfma_step(const bf16* __restrict__ Wl, int l15, int quad,
                                          bf16x8 a0, bf16x8 a1, int ks, floatx4 acc[2][8]) {
#pragma unroll
  for (int nt = 0; nt < 8; ++nt) {
    int n = nt * 16 + l15;
    bf16x8 b = *(const bf16x8*)(Wl + n * 64 + ((((ks >> 3) + quad) ^ (n & 7)) << 3));
    acc[0][nt] = __builtin_amdgcn_mfma_f32_16x16x32_bf16(a0, b, acc[0][nt], 0, 0, 0);
    acc[1][nt] = __builtin_amdgcn_mfma_f32_16x16x32_bf16(a1, b, acc[1][nt], 0, 0, 0);
  }
}

// X tile: [128][128] bf16, 16B-chunk XOR swizzle (bijective per row).
__device__ __forceinline__ int xidx(int row, int col) {
  return row * 128 + ((((col >> 3) ^ (row & 7))) << 3) + (col & 7);
}

// ---------------- pre kernel: P[n] = h[n] @ [W1a | W1b], bf16, BLOCKED layout ----
// P[node*256 + half*128 + l15*8 + nt] = (h @ W_e1[half*128 rows])[nt*16 + l15]
// Blocked so an edge lane's 8 accumulator columns {nt*16+l15} are one 16B load.
__global__ __launch_bounds__(256, 3) void pre_kernel(
    const bf16* __restrict__ nfb, const bf16* __restrict__ We1t,
    bf16* __restrict__ P) {
  __shared__ __align__(16) bf16 Wl[128 * 64];
  const int tid = threadIdx.x;
  const int lane = tid & 63;
  const int wv = tid >> 6;
  const int l15 = lane & 15;
  const int quad = lane >> 4;
  const int r0 = wv * 32;
  const int n0 = blockIdx.x * 128;

  bf16x8 A[2][2][2];  // [c2][t][s] : nfb cols c2*64 + s*32 + quad*8
#pragma unroll
  for (int c2 = 0; c2 < 2; ++c2)
#pragma unroll
    for (int t = 0; t < 2; ++t) {
      int n = n0 + r0 + t * 16 + l15;
      bool ok = n < N_NODES;
#pragma unroll
      for (int s = 0; s < 2; ++s) {
        bf16x8 f = {};
        if (ok) f = *(const bf16x8*)(nfb + (size_t)n * 128 + c2 * 64 + s * 32 + quad * 8);
        A[c2][t][s] = f;
      }
    }

  const floatx4 z4 = {0.f, 0.f, 0.f, 0.f};
#pragma unroll
  for (int h = 0; h < 2; ++h) {
    floatx4 acc[2][8];
#pragma unroll
    for (int t = 0; t < 2; ++t)
#pragma unroll
      for (int nt = 0; nt < 8; ++nt) acc[t][nt] = z4;
#pragma unroll
    for (int c2 = 0; c2 < 2; ++c2) {
      __syncthreads();
      stage_w(Wl, We1t, 320, h * 2 + c2, tid);
      __syncthreads();
      mfma_step(Wl, l15, quad, A[c2][0][0], A[c2][1][0], 0, acc);
      mfma_step(Wl, l15, quad, A[c2][0][1], A[c2][1][1], 32, acc);
    }
#pragma unroll
    for (int t = 0; t < 2; ++t)
#pragma unroll
      for (int i = 0; i < 4; ++i) {
        int node = n0 + r0 + t * 16 + quad * 4 + i;
        if (node < N_NODES) {
          bf16x8 v;
#pragma unroll
          for (int j = 0; j < 8; ++j) v[j] = (bf16)acc[t][j][i];
          *(bf16x8*)(P + (size_t)node * 256 + h * 128 + l15 * 8) = v;
        }
      }
  }
}

// ---------------- edge kernel: 128 edges/block, 4 waves x 32 rows ----------------
// e1's K=256 node part replaced by acc init from bf16 P (one gather burst).
__global__ __launch_bounds__(256, 3) void edge_kernel(
    const bf16* __restrict__ P, const float* __restrict__ coords,
    const float* __restrict__ ef,
    const bf16* __restrict__ We1t, const float* __restrict__ be1,
    const bf16* __restrict__ We2t, const float* __restrict__ be2,
    const bf16* __restrict__ Wc1t, const float* __restrict__ bc1,
    const float* __restrict__ Wc, const float* __restrict__ Wa,
    const float* __restrict__ ba,
    const int* __restrict__ src, const int* __restrict__ dst,
    float* __restrict__ m_agg, float* __restrict__ agg, float* __restrict__ cnt) {
  __shared__ __align__(16) bf16 X[128 * 128];  // h1, then gated m (rows wave-private)
  __shared__ __align__(16) bf16 Wl[128 * 64];  // swizzled W chunk
  __shared__ int sIdx[128], dIdx[128];
  __shared__ float cdL[128][3];
  __shared__ float radL[128];

  const int tid = threadIdx.x;
  const int lane = tid & 63;
  const int wv = tid >> 6;
  const int l15 = lane & 15;
  const int quad = lane >> 4;
  const int r0 = wv * 32;
  const int e0 = blockIdx.x * 128;

  if (tid < 128) {
    int e = e0 + tid;
    int s = src[e], d = dst[e];
    if ((unsigned)s >= N_NODES) s = 0;
    if ((unsigned)d >= N_NODES) d = 0;
    sIdx[tid] = s; dIdx[tid] = d;
    float dx = coords[s * 3 + 0] - coords[d * 3 + 0];
    float dy = coords[s * 3 + 1] - coords[d * 3 + 1];
    float dz = coords[s * 3 + 2] - coords[d * 3 + 2];
    cdL[tid][0] = dx; cdL[tid][1] = dy; cdL[tid][2] = dz;
    radL[tid] = dx * dx + dy * dy + dz * dz;
  }
  __syncthreads();

  // ---- acc init: Pa[src] + Pb[dst] — 16 independent 16B gathers per lane ----
  floatx4 acc[2][8];
#pragma unroll
  for (int t = 0; t < 2; ++t)
#pragma unroll
    for (int i = 0; i < 4; ++i) {
      int row = r0 + t * 16 + quad * 4 + i;
      bf16x8 pa = *(const bf16x8*)(P + (size_t)sIdx[row] * 256 + l15 * 8);
      bf16x8 pb = *(const bf16x8*)(P + (size_t)dIdx[row] * 256 + 128 + l15 * 8);
#pragma unroll
      for (int nt = 0; nt < 8; ++nt) acc[t][nt][i] = (float)pa[nt] + (float)pb[nt];
    }

  // ---- radial/ef A-frags (m_in cols 256..319) ----
  bf16x8 aef[2][2];
#pragma unroll
  for (int t = 0; t < 2; ++t) {
    int row = r0 + t * 16 + l15;
#pragma unroll
    for (int s = 0; s < 2; ++s)
#pragma unroll
      for (int jj = 0; jj < 8; ++jj) {
        int k = s * 32 + quad * 8 + jj;   // m_in col 256+k
        float v = 0.f;
        if (k == 0) v = radL[row];
        else if (k <= 32) v = ef[(size_t)(e0 + row) * 32 + (k - 1)];
        aef[t][s][jj] = (bf16)v;
      }
  }

  // ---- chunk 0: e1 radial/ef (We1t kc=4) ----
  stage_w(Wl, We1t, 320, 4, tid);
  __syncthreads();
  mfma_step(Wl, l15, quad, aef[0][0], aef[1][0], 0, acc);
  mfma_step(Wl, l15, quad, aef[0][1], aef[1][1], 32, acc);
  // epilogue e1: h1 = silu(acc+b) -> X (rows wave-private)
#pragma unroll
  for (int t = 0; t < 2; ++t)
#pragma unroll
    for (int nt = 0; nt < 8; ++nt) {
      int col = nt * 16 + l15;
      float b = be1[col];
#pragma unroll
      for (int i = 0; i < 4; ++i) {
        X[xidx(r0 + t * 16 + quad * 4 + i, col)] = (bf16)silu_f(acc[t][nt][i] + b);
        acc[t][nt][i] = 0.f;
      }
    }

  // ---- layer e2: K=128, A from X ----
  for (int kc = 0; kc < 2; ++kc) {
    __syncthreads();
    bf16x8 a[2][2];
#pragma unroll
    for (int t = 0; t < 2; ++t) {
      int row = r0 + t * 16 + l15;
      a[t][0] = *(const bf16x8*)(X + xidx(row, kc * 64 + quad * 8));
      a[t][1] = *(const bf16x8*)(X + xidx(row, kc * 64 + quad * 8 + 32));
    }
    stage_w(Wl, We2t, 128, kc, tid);
    __syncthreads();
    mfma_step(Wl, l15, quad, a[0][0], a[1][0], 0, acc);
    mfma_step(Wl, l15, quad, a[0][1], a[1][1], 32, acc);
  }
  // epilogue e2: silu, attention gate, write gated m to X, scatter m_agg
  float part[2][4] = {{0.f, 0.f, 0.f, 0.f}, {0.f, 0.f, 0.f, 0.f}};
#pragma unroll
  for (int t = 0; t < 2; ++t)
#pragma unroll
    for (int nt = 0; nt < 8; ++nt) {
      int col = nt * 16 + l15;
      float b = be2[col], wa = Wa[col];
#pragma unroll
      for (int i = 0; i < 4; ++i) {
        float v = silu_f(acc[t][nt][i] + b);
        acc[t][nt][i] = v;
        part[t][i] += v * wa;
      }
    }
#pragma unroll
  for (int off = 1; off < 16; off <<= 1)
#pragma unroll
    for (int t = 0; t < 2; ++t)
#pragma unroll
      for (int i = 0; i < 4; ++i) part[t][i] += __shfl_xor(part[t][i], off, 64);
  float ba_f = ba[0];
#pragma unroll
  for (int t = 0; t < 2; ++t)
#pragma unroll
    for (int i = 0; i < 4; ++i) {
      float g = sigm_f(part[t][i] + ba_f);
#pragma unroll
      for (int nt = 0; nt < 8; ++nt) acc[t][nt][i] *= g;
    }
#pragma unroll
  for (int t = 0; t < 2; ++t)
#pragma unroll
    for (int nt = 0; nt < 8; ++nt) {
      int col = nt * 16 + l15;
#pragma unroll
      for (int i = 0; i < 4; ++i)
        X[xidx(r0 + t * 16 + quad * 4 + i, col)] = (bf16)acc[t][nt][i];
    }
  // scatter gated m (f32 atomics) — issued early so they overlap coord layer
#pragma unroll
  for (int t = 0; t < 2; ++t)
#pragma unroll
    for (int i = 0; i < 4; ++i) {
      int row = r0 + t * 16 + quad * 4 + i;
      size_t base = (size_t)dIdx[row] * 128;
#pragma unroll
      for (int nt = 0; nt < 8; ++nt)
        atomicAdd(&m_agg[base + nt * 16 + l15], acc[t][nt][i]);
    }
  const floatx4 z4 = {0.f, 0.f, 0.f, 0.f};
#pragma unroll
  for (int t = 0; t < 2; ++t)
#pragma unroll
    for (int nt = 0; nt < 8; ++nt) acc[t][nt] = z4;

  // ---- coord layer: K=128, A = gated m from X ----
  for (int kc = 0; kc < 2; ++kc) {
    __syncthreads();
    bf16x8 a[2][2];
#pragma unroll
    for (int t = 0; t < 2; ++t) {
      int row = r0 + t * 16 + l15;
      a[t][0] = *(const bf16x8*)(X + xidx(row, kc * 64 + quad * 8));
      a[t][1] = *(const bf16x8*)(X + xidx(row, kc * 64 + quad * 8 + 32));
    }
    stage_w(Wl, Wc1t, 128, kc, tid);
    __syncthreads();
    mfma_step(Wl, l15, quad, a[0][0], a[1][0], 0, acc);
    mfma_step(Wl, l15, quad, a[0][1], a[1][1], 32, acc);
  }
  float partc[2][4] = {{0.f, 0.f, 0.f, 0.f}, {0.f, 0.f, 0.f, 0.f}};
#pragma unroll
  for (int t = 0; t < 2; ++t)
#pragma unroll
    for (int nt = 0; nt < 8; ++nt) {
      int col = nt * 16 + l15;
      float b = bc1[col], wc = Wc[col];
#pragma unroll
      for (int i = 0; i < 4; ++i) partc[t][i] += silu_f(acc[t][nt][i] + b) * wc;
    }
#pragma unroll
  for (int off = 1; off < 16; off <<= 1)
#pragma unroll
    for (int t = 0; t < 2; ++t)
#pragma unroll
      for (int i = 0; i < 4; ++i) partc[t][i] += __shfl_xor(partc[t][i], off, 64);
  if (l15 == 0) {
#pragma unroll
    for (int t = 0; t < 2; ++t)
#pragma unroll
      for (int i = 0; i < 4; ++i) {
        int row = r0 + t * 16 + quad * 4 + i;
        int d = dIdx[row];
        float c = partc[t][i];
        atomicAdd(&agg[d * 3 + 0], cdL[row][0] * c);
        atomicAdd(&agg[d * 3 + 1], cdL[row][1] * c);
        atomicAdd(&agg[d * 3 + 2], cdL[row][2] * c);
        atomicAdd(&cnt[d], 1.0f);
      }
  }
}

// ---------------- node kernel: 128 nodes/block ----------------
__global__ __launch_bounds__(256, 3) void node_kernel(
    const bf16* __restrict__ nfb, const float* __restrict__ nf,
    const float* __restrict__ coords,
    const bf16* __restrict__ Wn1t, const float* __restrict__ bn1,
    const bf16* __restrict__ Wn2t, const float* __restrict__ bn2,
    const float* __restrict__ m_agg, const float* __restrict__ agg,
    const float* __restrict__ cnt,
    float* __restrict__ h_out, float* __restrict__ c_out) {
  __shared__ __align__(16) bf16 X[128 * 128];
  __shared__ __align__(16) bf16 Wl[128 * 64];

  const int tid = threadIdx.x;
  const int lane = tid & 63;
  const int wv = tid >> 6;
  const int l15 = lane & 15;
  const int quad = lane >> 4;
  const int r0 = wv * 32;
  const int n0 = blockIdx.x * 128;

  if (tid < 128) {
    int n = n0 + tid;
    if (n < N_NODES) {
      float inv = 1.f / fmaxf(cnt[n], 1.f);
#pragma unroll
      for (int j = 0; j < 3; ++j)
        c_out[n * 3 + j] = coords[n * 3 + j] + agg[n * 3 + j] * inv;
    }
  }

  const floatx4 z4 = {0.f, 0.f, 0.f, 0.f};
  floatx4 acc[2][8];
#pragma unroll
  for (int t = 0; t < 2; ++t)
#pragma unroll
    for (int nt = 0; nt < 8; ++nt) acc[t][nt] = z4;

  // ---- n1: K=256 (cols 0-127 h from nfb, 128-255 m_agg f32->bf16) ----
  for (int kc = 0; kc < 4; ++kc) {
    __syncthreads();
    bf16x8 a[2][2];
#pragma unroll
    for (int t = 0; t < 2; ++t) {
      int n = n0 + r0 + t * 16 + l15;
      bool ok = n < N_NODES;
#pragma unroll
      for (int s = 0; s < 2; ++s) {
        if (kc < 2) {
          bf16x8 f = {};
          if (ok) f = *(const bf16x8*)(nfb + (size_t)n * 128 + kc * 64 + s * 32 + quad * 8);
          a[t][s] = f;
        } else {
          bf16x8 f;
          if (ok) {
            const float* p = m_agg + (size_t)n * 128 + (kc - 2) * 64 + s * 32 + quad * 8;
            float4 u0 = *(const float4*)(p);
            float4 u1 = *(const float4*)(p + 4);
            f[0] = (bf16)u0.x; f[1] = (bf16)u0.y; f[2] = (bf16)u0.z; f[3] = (bf16)u0.w;
            f[4] = (bf16)u1.x; f[5] = (bf16)u1.y; f[6] = (bf16)u1.z; f[7] = (bf16)u1.w;
          } else {
            bf16x8 zz = {};
            f = zz;
          }
          a[t][s] = f;
        }
      }
    }
    stage_w(Wl, Wn1t, 256, kc, tid);
    __syncthreads();
    mfma_step(Wl, l15, quad, a[0][0], a[1][0], 0, acc);
    mfma_step(Wl, l15, quad, a[0][1], a[1][1], 32, acc);
  }
#pragma unroll
  for (int t = 0; t < 2; ++t)
#pragma unroll
    for (int nt = 0; nt < 8; ++nt) {
      int col = nt * 16 + l15;
      float b = bn1[col];
#pragma unroll
      for (int i = 0; i < 4; ++i) {
        X[xidx(r0 + t * 16 + quad * 4 + i, col)] = (bf16)silu_f(acc[t][nt][i] + b);
        acc[t][nt][i] = 0.f;
      }
    }

  // ---- n2: K=128, A = h1 from X; residual from f32 nf ----
  for (int kc = 0; kc < 2; ++kc) {
    __syncthreads();
    bf16x8 a[2][2];
#pragma unroll
    for (int t = 0; t < 2; ++t) {
      int row = r0 + t * 16 + l15;
      a[t][0] = *(const bf16x8*)(X + xidx(row, kc * 64 + quad * 8));
      a[t][1] = *(const bf16x8*)(X + xidx(row, kc * 64 + quad * 8 + 32));
    }
    stage_w(Wl, Wn2t, 128, kc, tid);
    __syncthreads();
    mfma_step(Wl, l15, quad, a[0][0], a[1][0], 0, acc);
    mfma_step(Wl, l15, quad, a[0][1], a[1][1], 32, acc);
  }
#pragma unroll
  for (int t = 0; t < 2; ++t)
#pragma unroll
    for (int nt = 0; nt < 8; ++nt) {
      int col = nt * 16 + l15;
      float b = bn2[col];
#pragma unroll
      for (int i = 0; i < 4; ++i) {
        int n = n0 + r0 + t * 16 + quad * 4 + i;
        if (n < N_NODES)
          h_out[(size_t)n * 128 + col] = nf[(size_t)n * 128 + col] + acc[t][nt][i] + b;
      }
    }
}

extern "C" void kernel_launch(void* const* d_in, const int* in_sizes, int n_in,
                              void* d_out, int out_size, void* d_ws, size_t ws_size,
                              hipStream_t stream) {
  const float* nf     = (const float*)d_in[0];
  const float* coords = (const float*)d_in[1];
  const float* ef     = (const float*)d_in[2];
  const float* We1    = (const float*)d_in[3];
  const float* be1    = (const float*)d_in[4];
  const float* We2    = (const float*)d_in[5];
  const float* be2    = (const float*)d_in[6];
  const float* Wn1    = (const float*)d_in[7];
  const float* bn1    = (const float*)d_in[8];
  const float* Wn2    = (const float*)d_in[9];
  const float* bn2    = (const float*)d_in[10];
  const float* Wc1    = (const float*)d_in[11];
  const float* bc1    = (const float*)d_in[12];
  const float* Wc     = (const float*)d_in[13];
  const float* Wa     = (const float*)d_in[14];
  const float* ba     = (const float*)d_in[15];
  const int*   src    = (const int*)d_in[16];
  const int*   dst    = (const int*)d_in[17];

  float* agg   = (float*)d_ws;                      // 3N
  float* cnt   = agg + (size_t)3 * N_NODES;         // N
  float* m_agg = cnt + N_NODES;                     // N*128
  bf16* nfb    = (bf16*)(m_agg + (size_t)N_NODES * 128);
  bf16* Wt     = nfb + (size_t)N_NODES * 128;       // 122880 bf16
  bf16* P      = Wt + 122880;                       // N*256 bf16 (blocked)
  const int offE1 = 0;
  const int offE2 = 128 * 320;
  const int offC1 = offE2 + 128 * 128;
  const int offN1 = offC1 + 128 * 128;
  const int offN2 = offN1 + 128 * 256;

  size_t zb = ((size_t)3 * N_NODES + N_NODES + (size_t)N_NODES * 128) * sizeof(float);
  hipMemsetAsync(d_ws, 0, zb, stream);

  prep_nf<<<(N_NODES * 128) / (256 * 4), 256, 0, stream>>>(nf, nfb);
  TW tw;
  tw.s[0] = We1; tw.K[0] = 289; tw.Kp[0] = 320; tw.off[0] = offE1;
  tw.s[1] = We2; tw.K[1] = 128; tw.Kp[1] = 128; tw.off[1] = offE2;
  tw.s[2] = Wc1; tw.K[2] = 128; tw.Kp[2] = 128; tw.off[2] = offC1;
  tw.s[3] = Wn1; tw.K[3] = 256; tw.Kp[3] = 256; tw.off[3] = offN1;
  tw.s[4] = Wn2; tw.K[4] = 128; tw.Kp[4] = 128; tw.off[4] = offN2;
  prep_tw<<<480, 256, 0, stream>>>(tw, Wt);

  pre_kernel<<<(N_NODES + 127) / 128, 256, 0, stream>>>(nfb, Wt + offE1, P);

  float* h_out = (float*)d_out;
  float* c_out = h_out + (size_t)N_NODES * 128;

  edge_kernel<<<N_EDGES / 128, 256, 0, stream>>>(
      P, coords, ef, Wt + offE1, be1, Wt + offE2, be2, Wt + offC1, bc1,
      Wc, Wa, ba, src, dst, m_agg, agg, cnt);
  node_kernel<<<(N_NODES + 127) / 128, 256, 0, stream>>>(
      nfb, nf, coords, Wt + offN1, bn1, Wt + offN2, bn2,
      m_agg, agg, cnt, h_out, c_out);
}

// Round 6
// 668.675 us; speedup vs baseline: 1.8199x; 1.0933x over previous
//
#include <hip/hip_runtime.h>

typedef __bf16 bf16;
typedef __bf16 bf16x8 __attribute__((ext_vector_type(8)));
typedef float floatx4 __attribute__((ext_vector_type(4)));

#define N_NODES 50000
#define N_EDGES 800000

__device__ __forceinline__ float silu_f(float x) {
  float t = fminf(fmaxf(x, -40.f), 40.f);
  return x / (1.f + __expf(-t));
}
__device__ __forceinline__ float sigm_f(float x) {
  float t = fminf(fmaxf(x, -40.f), 40.f);
  return 1.f / (1.f + __expf(-t));
}

__device__ __forceinline__ void atomic_pk_bf16(bf16* p, unsigned v) {
  asm volatile("global_atomic_pk_add_bf16 %0, %1, off" : : "v"(p), "v"(v) : "memory");
}

// ---------------- prep: f32 -> bf16 ----------------
__global__ void prep_nf(const float* __restrict__ src, bf16* __restrict__ dst) {
  int i = (blockIdx.x * 256 + threadIdx.x) * 4;
  float4 v = *(const float4*)(src + i);
  bf16 o[4] = {(bf16)v.x, (bf16)v.y, (bf16)v.z, (bf16)v.w};
  *(float2*)(dst + i) = *(float2*)o;
}

// transpose+convert weights: Wt[n*Kp + k] = W[k*128 + n], zero-padded to Kp
struct TW { const float* s[5]; int K[5]; int Kp[5]; int off[5]; };
__global__ void prep_tw(TW j, bf16* __restrict__ out) {
  int g = blockIdx.x * 256 + threadIdx.x;
#pragma unroll
  for (int t = 0; t < 5; ++t) {
    int sz = 128 * j.Kp[t];
    if (g < sz) {
      int n = g / j.Kp[t], k = g - n * j.Kp[t];
      out[j.off[t] + g] = (k < j.K[t]) ? (bf16)j.s[t][(size_t)k * 128 + n] : (bf16)0.f;
      return;
    }
    g -= sz;
  }
}

// ---------------- counting sort of edges by dst ----------------
__global__ void hist_k(const int* __restrict__ dst, int* __restrict__ deg) {
  int e = blockIdx.x * 256 + threadIdx.x;
  if (e < N_EDGES) {
    int d = dst[e];
    if ((unsigned)d >= N_NODES) d = 0;
    atomicAdd(&deg[d], 1);
  }
}

__global__ void scan_k(const int* __restrict__ deg, int* __restrict__ start) {
  __shared__ int part[256];
  int t = threadIdx.x;
  int c0 = t * 196, c1 = min(N_NODES, c0 + 196);
  int s = 0;
  for (int i = c0; i < c1; ++i) s += deg[i];
  part[t] = s;
  __syncthreads();
  for (int off = 1; off < 256; off <<= 1) {
    int u = (t >= off) ? part[t - off] : 0;
    __syncthreads();
    part[t] += u;
    __syncthreads();
  }
  int run = part[t] - s;  // exclusive base
  for (int i = c0; i < c1; ++i) { start[i] = run; run += deg[i]; }
}

__global__ void scatter_k(const int* __restrict__ src, const int* __restrict__ dst,
                          int* __restrict__ start, int* __restrict__ eS,
                          int* __restrict__ srcS, int* __restrict__ dstS) {
  int e = blockIdx.x * 256 + threadIdx.x;
  if (e >= N_EDGES) return;
  int s = src[e], d = dst[e];
  if ((unsigned)s >= N_NODES) s = 0;
  if ((unsigned)d >= N_NODES) d = 0;
  int pos = atomicAdd(&start[d], 1);
  eS[pos] = e; srcS[pos] = s; dstS[pos] = d;
}

// stage one 64-wide K-chunk of Wt into LDS [128][64] with XOR chunk swizzle.
__device__ __forceinline__ void stage_w(bf16* __restrict__ Wl, const bf16* __restrict__ Wt,
                                        int Kp, int kc, int tid) {
#pragma unroll
  for (int jj = 0; jj < 4; ++jj) {
    int g = tid + jj * 256;
    int n = g >> 3, c = g & 7;
    *(float4*)(Wl + n * 64 + ((c ^ (n & 7)) << 3)) =
        *(const float4*)(Wt + (size_t)n * Kp + kc * 64 + c * 8);
  }
}

// one 32-wide k-step: 8 col-tiles, B loaded once, 2 row-subtiles share it.
__device__ __forceinline__ void mfma_step(const bf16* __restrict__ Wl, int l15, int quad,
                                          bf16x8 a0, bf16x8 a1, int ks, floatx4 acc[2][8]) {
#pragma unroll
  for (int nt = 0; nt < 8; ++nt) {
    int n = nt * 16 + l15;
    bf16x8 b = *(const bf16x8*)(Wl + n * 64 + ((((ks >> 3) + quad) ^ (n & 7)) << 3));
    acc[0][nt] = __builtin_amdgcn_mfma_f32_16x16x32_bf16(a0, b, acc[0][nt], 0, 0, 0);
    acc[1][nt] = __builtin_amdgcn_mfma_f32_16x16x32_bf16(a1, b, acc[1][nt], 0, 0, 0);
  }
}

// X tile: [128][128] bf16, 16B-chunk XOR swizzle (bijective per row).
__device__ __forceinline__ int xidx(int row, int col) {
  return row * 128 + ((((col >> 3) ^ (row & 7))) << 3) + (col & 7);
}

// ---------------- pre kernel: P[n] = h[n] @ [W1a | W1b], bf16, BLOCKED layout ----
__global__ __launch_bounds__(256, 3) void pre_kernel(
    const bf16* __restrict__ nfb, const bf16* __restrict__ We1t,
    bf16* __restrict__ P) {
  __shared__ __align__(16) bf16 Wl[128 * 64];
  const int tid = threadIdx.x;
  const int lane = tid & 63;
  const int wv = tid >> 6;
  const int l15 = lane & 15;
  const int quad = lane >> 4;
  const int r0 = wv * 32;
  const int n0 = blockIdx.x * 128;

  bf16x8 A[2][2][2];
#pragma unroll
  for (int c2 = 0; c2 < 2; ++c2)
#pragma unroll
    for (int t = 0; t < 2; ++t) {
      int n = n0 + r0 + t * 16 + l15;
      bool ok = n < N_NODES;
#pragma unroll
      for (int s = 0; s < 2; ++s) {
        bf16x8 f = {};
        if (ok) f = *(const bf16x8*)(nfb + (size_t)n * 128 + c2 * 64 + s * 32 + quad * 8);
        A[c2][t][s] = f;
      }
    }

  const floatx4 z4 = {0.f, 0.f, 0.f, 0.f};
#pragma unroll
  for (int h = 0; h < 2; ++h) {
    floatx4 acc[2][8];
#pragma unroll
    for (int t = 0; t < 2; ++t)
#pragma unroll
      for (int nt = 0; nt < 8; ++nt) acc[t][nt] = z4;
#pragma unroll
    for (int c2 = 0; c2 < 2; ++c2) {
      __syncthreads();
      stage_w(Wl, We1t, 320, h * 2 + c2, tid);
      __syncthreads();
      mfma_step(Wl, l15, quad, A[c2][0][0], A[c2][1][0], 0, acc);
      mfma_step(Wl, l15, quad, A[c2][0][1], A[c2][1][1], 32, acc);
    }
#pragma unroll
    for (int t = 0; t < 2; ++t)
#pragma unroll
      for (int i = 0; i < 4; ++i) {
        int node = n0 + r0 + t * 16 + quad * 4 + i;
        if (node < N_NODES) {
          bf16x8 v;
#pragma unroll
          for (int j = 0; j < 8; ++j) v[j] = (bf16)acc[t][j][i];
          *(bf16x8*)(P + (size_t)node * 256 + h * 128 + l15 * 8) = v;
        }
      }
  }
}

// ---------------- edge kernel: 128 dst-sorted edges/block ----------------
__global__ __launch_bounds__(256, 3) void edge_kernel(
    const bf16* __restrict__ P, const float* __restrict__ coords,
    const float* __restrict__ ef,
    const bf16* __restrict__ We1t, const float* __restrict__ be1,
    const bf16* __restrict__ We2t, const float* __restrict__ be2,
    const bf16* __restrict__ Wc1t, const float* __restrict__ bc1,
    const float* __restrict__ Wc, const float* __restrict__ Wa,
    const float* __restrict__ ba,
    const int* __restrict__ eS, const int* __restrict__ srcS,
    const int* __restrict__ dstS,
    bf16* __restrict__ m_agg, float* __restrict__ agg) {
  __shared__ __align__(16) bf16 X[128 * 128];  // h1, then gated m (rows wave-private)
  __shared__ __align__(16) bf16 Wl[128 * 64];  // swizzled W chunk
  __shared__ float cdL[128][3];
  __shared__ float radL[128];
  __shared__ float transL[128][3];
  __shared__ int sHeadRow[130];
  __shared__ int sND, sC0;

  const int tid = threadIdx.x;
  const int lane = tid & 63;
  const int wv = tid >> 6;
  const int l15 = lane & 15;
  const int quad = lane >> 4;
  const int r0 = wv * 32;
  const int e0 = blockIdx.x * 128;

  if (tid < 128) {
    int s = srcS[e0 + tid], d = dstS[e0 + tid];
    float dx = coords[s * 3 + 0] - coords[d * 3 + 0];
    float dy = coords[s * 3 + 1] - coords[d * 3 + 1];
    float dz = coords[s * 3 + 2] - coords[d * 3 + 2];
    cdL[tid][0] = dx; cdL[tid][1] = dy; cdL[tid][2] = dz;
    radL[tid] = dx * dx + dy * dy + dz * dz;
  }

  // dst-segment heads via boundary-flag ballot prefix (rows dst-sorted)
  bool flag = false; int incl = 0;
  if (tid < 128) {  // waves 0,1 entirely
    int d = dstS[e0 + tid];
    flag = (tid == 0) || (d != dstS[e0 + tid - 1]);
    unsigned long long m = __ballot(flag);
    incl = __popcll(m & (~0ull >> (63 - lane)));
    if (lane == 63 && tid < 64) sC0 = incl;
  }
  __syncthreads();
  if (tid < 128) {
    int slot = ((tid >= 64) ? sC0 : 0) + incl - 1;
    if (flag) sHeadRow[slot] = tid;
    if (tid == 127) sND = slot + 1;
  }
  __syncthreads();
  if (tid == 0) sHeadRow[sND] = 128;  // sentinel (fenced by later barriers)

  // ---- acc init: Pa[src] + Pb[dst] — independent 16B gather burst ----
  floatx4 acc[2][8];
#pragma unroll
  for (int t = 0; t < 2; ++t)
#pragma unroll
    for (int i = 0; i < 4; ++i) {
      int row = r0 + t * 16 + quad * 4 + i;
      int sN = srcS[e0 + row], dN = dstS[e0 + row];
      bf16x8 pa = *(const bf16x8*)(P + (size_t)sN * 256 + l15 * 8);
      bf16x8 pb = *(const bf16x8*)(P + (size_t)dN * 256 + 128 + l15 * 8);
#pragma unroll
      for (int nt = 0; nt < 8; ++nt) acc[t][nt][i] = (float)pa[nt] + (float)pb[nt];
    }

  // ---- radial/ef A-frags (m_in cols 256..319), ef gathered via eS ----
  bf16x8 aef[2][2];
#pragma unroll
  for (int t = 0; t < 2; ++t) {
    int row = r0 + t * 16 + l15;
    int eL = eS[e0 + row];
#pragma unroll
    for (int s = 0; s < 2; ++s)
#pragma unroll
      for (int jj = 0; jj < 8; ++jj) {
        int k = s * 32 + quad * 8 + jj;
        float v = 0.f;
        if (k == 0) v = radL[row];
        else if (k <= 32) v = ef[(size_t)eL * 32 + (k - 1)];
        aef[t][s][jj] = (bf16)v;
      }
  }

  // ---- chunk 0: e1 radial/ef (We1t kc=4) ----
  stage_w(Wl, We1t, 320, 4, tid);
  __syncthreads();
  mfma_step(Wl, l15, quad, aef[0][0], aef[1][0], 0, acc);
  mfma_step(Wl, l15, quad, aef[0][1], aef[1][1], 32, acc);
#pragma unroll
  for (int t = 0; t < 2; ++t)
#pragma unroll
    for (int nt = 0; nt < 8; ++nt) {
      int col = nt * 16 + l15;
      float b = be1[col];
#pragma unroll
      for (int i = 0; i < 4; ++i) {
        X[xidx(r0 + t * 16 + quad * 4 + i, col)] = (bf16)silu_f(acc[t][nt][i] + b);
        acc[t][nt][i] = 0.f;
      }
    }

  // ---- layer e2: K=128, A from X ----
  for (int kc = 0; kc < 2; ++kc) {
    __syncthreads();
    bf16x8 a[2][2];
#pragma unroll
    for (int t = 0; t < 2; ++t) {
      int row = r0 + t * 16 + l15;
      a[t][0] = *(const bf16x8*)(X + xidx(row, kc * 64 + quad * 8));
      a[t][1] = *(const bf16x8*)(X + xidx(row, kc * 64 + quad * 8 + 32));
    }
    stage_w(Wl, We2t, 128, kc, tid);
    __syncthreads();
    mfma_step(Wl, l15, quad, a[0][0], a[1][0], 0, acc);
    mfma_step(Wl, l15, quad, a[0][1], a[1][1], 32, acc);
  }
  // epilogue e2: silu, attention gate, write gated m to X
  float part[2][4] = {{0.f, 0.f, 0.f, 0.f}, {0.f, 0.f, 0.f, 0.f}};
#pragma unroll
  for (int t = 0; t < 2; ++t)
#pragma unroll
    for (int nt = 0; nt < 8; ++nt) {
      int col = nt * 16 + l15;
      float b = be2[col], wa = Wa[col];
#pragma unroll
      for (int i = 0; i < 4; ++i) {
        float v = silu_f(acc[t][nt][i] + b);
        acc[t][nt][i] = v;
        part[t][i] += v * wa;
      }
    }
#pragma unroll
  for (int off = 1; off < 16; off <<= 1)
#pragma unroll
    for (int t = 0; t < 2; ++t)
#pragma unroll
      for (int i = 0; i < 4; ++i) part[t][i] += __shfl_xor(part[t][i], off, 64);
  float ba_f = ba[0];
#pragma unroll
  for (int t = 0; t < 2; ++t)
#pragma unroll
    for (int i = 0; i < 4; ++i) {
      float g = sigm_f(part[t][i] + ba_f);
#pragma unroll
      for (int nt = 0; nt < 8; ++nt) acc[t][nt][i] *= g;
    }
#pragma unroll
  for (int t = 0; t < 2; ++t)
#pragma unroll
    for (int nt = 0; nt < 8; ++nt) {
      int col = nt * 16 + l15;
#pragma unroll
      for (int i = 0; i < 4; ++i)
        X[xidx(r0 + t * 16 + quad * 4 + i, col)] = (bf16)acc[t][nt][i];
    }
  const floatx4 z4 = {0.f, 0.f, 0.f, 0.f};
#pragma unroll
  for (int t = 0; t < 2; ++t)
#pragma unroll
    for (int nt = 0; nt < 8; ++nt) acc[t][nt] = z4;

  // ---- coord layer kc=0; after the barrier X (gated m) is block-visible:
  //      flush per-segment m sums (read X, sum f32, one pk-bf16 atomic each) ----
  {
    __syncthreads();
    bf16x8 a[2][2];
#pragma unroll
    for (int t = 0; t < 2; ++t) {
      int row = r0 + t * 16 + l15;
      a[t][0] = *(const bf16x8*)(X + xidx(row, quad * 8));
      a[t][1] = *(const bf16x8*)(X + xidx(row, quad * 8 + 32));
    }
    stage_w(Wl, Wc1t, 128, 0, tid);
    {
      int S = sND;
      for (int idx = tid; idx < S * 64; idx += 256) {
        int s = idx >> 6, c2 = idx & 63;
        int rA = sHeadRow[s], rB = sHeadRow[s + 1];
        float s0 = 0.f, s1 = 0.f;
        for (int r = rA; r < rB; ++r) {
          union { unsigned u; bf16 h[2]; } cv;
          cv.u = *(const unsigned*)(X + xidx(r, c2 * 2));
          s0 += (float)cv.h[0]; s1 += (float)cv.h[1];
        }
        union { unsigned u; bf16 h[2]; } pk;
        pk.h[0] = (bf16)s0; pk.h[1] = (bf16)s1;
        atomic_pk_bf16(m_agg + (size_t)dstS[e0 + rA] * 128 + c2 * 2, pk.u);
      }
    }
    __syncthreads();
    mfma_step(Wl, l15, quad, a[0][0], a[1][0], 0, acc);
    mfma_step(Wl, l15, quad, a[0][1], a[1][1], 32, acc);
  }
  // ---- coord layer kc=1 ----
  {
    __syncthreads();
    bf16x8 a[2][2];
#pragma unroll
    for (int t = 0; t < 2; ++t) {
      int row = r0 + t * 16 + l15;
      a[t][0] = *(const bf16x8*)(X + xidx(row, 64 + quad * 8));
      a[t][1] = *(const bf16x8*)(X + xidx(row, 64 + quad * 8 + 32));
    }
    stage_w(Wl, Wc1t, 128, 1, tid);
    __syncthreads();
    mfma_step(Wl, l15, quad, a[0][0], a[1][0], 0, acc);
    mfma_step(Wl, l15, quad, a[0][1], a[1][1], 32, acc);
  }
  // coord epilogue: per-row c, then per-segment agg flush
  float partc[2][4] = {{0.f, 0.f, 0.f, 0.f}, {0.f, 0.f, 0.f, 0.f}};
#pragma unroll
  for (int t = 0; t < 2; ++t)
#pragma unroll
    for (int nt = 0; nt < 8; ++nt) {
      int col = nt * 16 + l15;
      float b = bc1[col], wc = Wc[col];
#pragma unroll
      for (int i = 0; i < 4; ++i) partc[t][i] += silu_f(acc[t][nt][i] + b) * wc;
    }
#pragma unroll
  for (int off = 1; off < 16; off <<= 1)
#pragma unroll
    for (int t = 0; t < 2; ++t)
#pragma unroll
      for (int i = 0; i < 4; ++i) partc[t][i] += __shfl_xor(partc[t][i], off, 64);
  if (l15 == 0) {
#pragma unroll
    for (int t = 0; t < 2; ++t)
#pragma unroll
      for (int i = 0; i < 4; ++i) {
        int row = r0 + t * 16 + quad * 4 + i;
        float c = partc[t][i];
        transL[row][0] = cdL[row][0] * c;
        transL[row][1] = cdL[row][1] * c;
        transL[row][2] = cdL[row][2] * c;
      }
  }
  __syncthreads();
  {
    int S = sND;
    for (int idx = tid; idx < S * 3; idx += 256) {
      int s = idx / 3, j = idx - s * 3;
      int rA = sHeadRow[s], rB = sHeadRow[s + 1];
      float v = 0.f;
      for (int r = rA; r < rB; ++r) v += transL[r][j];
      atomicAdd(&agg[(size_t)dstS[e0 + rA] * 3 + j], v);
    }
  }
}

// ---------------- node kernel: 128 nodes/block ----------------
__global__ __launch_bounds__(256, 3) void node_kernel(
    const bf16* __restrict__ nfb, const float* __restrict__ nf,
    const float* __restrict__ coords,
    const bf16* __restrict__ Wn1t, const float* __restrict__ bn1,
    const bf16* __restrict__ Wn2t, const float* __restrict__ bn2,
    const bf16* __restrict__ m_agg, const float* __restrict__ agg,
    const int* __restrict__ deg,
    float* __restrict__ h_out, float* __restrict__ c_out) {
  __shared__ __align__(16) bf16 X[128 * 128];
  __shared__ __align__(16) bf16 Wl[128 * 64];

  const int tid = threadIdx.x;
  const int lane = tid & 63;
  const int wv = tid >> 6;
  const int l15 = lane & 15;
  const int quad = lane >> 4;
  const int r0 = wv * 32;
  const int n0 = blockIdx.x * 128;

  if (tid < 128) {
    int n = n0 + tid;
    if (n < N_NODES) {
      float inv = 1.f / fmaxf((float)deg[n], 1.f);
#pragma unroll
      for (int j = 0; j < 3; ++j)
        c_out[n * 3 + j] = coords[n * 3 + j] + agg[n * 3 + j] * inv;
    }
  }

  const floatx4 z4 = {0.f, 0.f, 0.f, 0.f};
  floatx4 acc[2][8];
#pragma unroll
  for (int t = 0; t < 2; ++t)
#pragma unroll
    for (int nt = 0; nt < 8; ++nt) acc[t][nt] = z4;

  // ---- n1: K=256 (cols 0-127 h from nfb, 128-255 m_agg bf16) ----
  for (int kc = 0; kc < 4; ++kc) {
    __syncthreads();
    bf16x8 a[2][2];
#pragma unroll
    for (int t = 0; t < 2; ++t) {
      int n = n0 + r0 + t * 16 + l15;
      bool ok = n < N_NODES;
      const bf16* base = (kc < 2) ? (nfb + (size_t)n * 128 + kc * 64)
                                  : (m_agg + (size_t)n * 128 + (kc - 2) * 64);
#pragma unroll
      for (int s = 0; s < 2; ++s) {
        bf16x8 f = {};
        if (ok) f = *(const bf16x8*)(base + s * 32 + quad * 8);
        a[t][s] = f;
      }
    }
    stage_w(Wl, Wn1t, 256, kc, tid);
    __syncthreads();
    mfma_step(Wl, l15, quad, a[0][0], a[1][0], 0, acc);
    mfma_step(Wl, l15, quad, a[0][1], a[1][1], 32, acc);
  }
#pragma unroll
  for (int t = 0; t < 2; ++t)
#pragma unroll
    for (int nt = 0; nt < 8; ++nt) {
      int col = nt * 16 + l15;
      float b = bn1[col];
#pragma unroll
      for (int i = 0; i < 4; ++i) {
        X[xidx(r0 + t * 16 + quad * 4 + i, col)] = (bf16)silu_f(acc[t][nt][i] + b);
        acc[t][nt][i] = 0.f;
      }
    }

  // ---- n2: K=128, A = h1 from X; residual from f32 nf ----
  for (int kc = 0; kc < 2; ++kc) {
    __syncthreads();
    bf16x8 a[2][2];
#pragma unroll
    for (int t = 0; t < 2; ++t) {
      int row = r0 + t * 16 + l15;
      a[t][0] = *(const bf16x8*)(X + xidx(row, kc * 64 + quad * 8));
      a[t][1] = *(const bf16x8*)(X + xidx(row, kc * 64 + quad * 8 + 32));
    }
    stage_w(Wl, Wn2t, 128, kc, tid);
    __syncthreads();
    mfma_step(Wl, l15, quad, a[0][0], a[1][0], 0, acc);
    mfma_step(Wl, l15, quad, a[0][1], a[1][1], 32, acc);
  }
#pragma unroll
  for (int t = 0; t < 2; ++t)
#pragma unroll
    for (int nt = 0; nt < 8; ++nt) {
      int col = nt * 16 + l15;
      float b = bn2[col];
#pragma unroll
      for (int i = 0; i < 4; ++i) {
        int n = n0 + r0 + t * 16 + quad * 4 + i;
        if (n < N_NODES)
          h_out[(size_t)n * 128 + col] = nf[(size_t)n * 128 + col] + acc[t][nt][i] + b;
      }
    }
}

extern "C" void kernel_launch(void* const* d_in, const int* in_sizes, int n_in,
                              void* d_out, int out_size, void* d_ws, size_t ws_size,
                              hipStream_t stream) {
  const float* nf     = (const float*)d_in[0];
  const float* coords = (const float*)d_in[1];
  const float* ef     = (const float*)d_in[2];
  const float* We1    = (const float*)d_in[3];
  const float* be1    = (const float*)d_in[4];
  const float* We2    = (const float*)d_in[5];
  const float* be2    = (const float*)d_in[6];
  const float* Wn1    = (const float*)d_in[7];
  const float* bn1    = (const float*)d_in[8];
  const float* Wn2    = (const float*)d_in[9];
  const float* bn2    = (const float*)d_in[10];
  const float* Wc1    = (const float*)d_in[11];
  const float* bc1    = (const float*)d_in[12];
  const float* Wc     = (const float*)d_in[13];
  const float* Wa     = (const float*)d_in[14];
  const float* ba     = (const float*)d_in[15];
  const int*   src    = (const int*)d_in[16];
  const int*   dst    = (const int*)d_in[17];

  // workspace layout (zeroed region first): deg | agg | m_agg(bf16) | rest
  int*   deg   = (int*)d_ws;                            // N
  float* agg   = (float*)(deg + N_NODES);               // 3N
  bf16*  m_agg = (bf16*)(agg + (size_t)3 * N_NODES);    // 128N bf16
  int*   start = (int*)(m_agg + (size_t)N_NODES * 128); // N
  int*   eS    = start + N_NODES;                       // E
  int*   srcS  = eS + N_EDGES;                          // E
  int*   dstS  = srcS + N_EDGES;                        // E
  bf16*  nfb   = (bf16*)(dstS + N_EDGES);               // 128N
  bf16*  Wt    = nfb + (size_t)N_NODES * 128;           // 122880
  bf16*  P     = Wt + 122880;                           // 256N (blocked)

  const int offE1 = 0;
  const int offE2 = 128 * 320;
  const int offC1 = offE2 + 128 * 128;
  const int offN1 = offC1 + 128 * 128;
  const int offN2 = offN1 + 128 * 256;

  size_t zb = (size_t)N_NODES * (4 + 12 + 256);  // deg + agg + m_agg
  hipMemsetAsync(d_ws, 0, zb, stream);

  prep_nf<<<(N_NODES * 128) / (256 * 4), 256, 0, stream>>>(nf, nfb);
  TW tw;
  tw.s[0] = We1; tw.K[0] = 289; tw.Kp[0] = 320; tw.off[0] = offE1;
  tw.s[1] = We2; tw.K[1] = 128; tw.Kp[1] = 128; tw.off[1] = offE2;
  tw.s[2] = Wc1; tw.K[2] = 128; tw.Kp[2] = 128; tw.off[2] = offC1;
  tw.s[3] = Wn1; tw.K[3] = 256; tw.Kp[3] = 256; tw.off[3] = offN1;
  tw.s[4] = Wn2; tw.K[4] = 128; tw.Kp[4] = 128; tw.off[4] = offN2;
  prep_tw<<<480, 256, 0, stream>>>(tw, Wt);

  hist_k<<<(N_EDGES + 255) / 256, 256, 0, stream>>>(dst, deg);
  scan_k<<<1, 256, 0, stream>>>(deg, start);
  scatter_k<<<(N_EDGES + 255) / 256, 256, 0, stream>>>(src, dst, start, eS, srcS, dstS);

  pre_kernel<<<(N_NODES + 127) / 128, 256, 0, stream>>>(nfb, Wt + offE1, P);

  float* h_out = (float*)d_out;
  float* c_out = h_out + (size_t)N_NODES * 128;

  edge_kernel<<<N_EDGES / 128, 256, 0, stream>>>(
      P, coords, ef, Wt + offE1, be1, Wt + offE2, be2, Wt + offC1, bc1,
      Wc, Wa, ba, eS, srcS, dstS, m_agg, agg);
  node_kernel<<<(N_NODES + 127) / 128, 256, 0, stream>>>(
      nfb, nf, coords, Wt + offN1, bn1, Wt + offN2, bn2,
      m_agg, agg, deg, h_out, c_out);
}